// Round 15
// baseline (162.258 us; speedup 1.0000x reference)
//
#include <hip/hip_runtime.h>

typedef __attribute__((ext_vector_type(4))) float f32x4;
typedef __attribute__((ext_vector_type(16))) float f32x16;
typedef __attribute__((ext_vector_type(8))) short bf16x8;
typedef __attribute__((ext_vector_type(4))) unsigned short u16x4;
typedef unsigned short u16;

#define DM 1024
#define NHEAD 16
#define DHEAD 64
#define QLEN 2048
#define MLEN 2048
#define KLEN 4096
#define QSCALE 0.18033688011112042f   // 0.125 * log2(e): softmax in exp2 domain

__device__ __forceinline__ float bf2f(u16 u) {
    unsigned i = ((unsigned)u) << 16; float f; __builtin_memcpy(&f, &i, 4); return f;
}
__device__ __forceinline__ u16 f2bf(float f) {
    unsigned i; __builtin_memcpy(&i, &f, 4);
    unsigned r = i + 0x7fffu + ((i >> 16) & 1u);
    return (u16)(r >> 16);
}
__device__ __forceinline__ float exp2_fast(float x) {
#if __has_builtin(__builtin_amdgcn_exp2f)
    return __builtin_amdgcn_exp2f(x);
#else
    return exp2f(x);
#endif
}
__device__ __forceinline__ unsigned cvtpk_bf16(float lo, float hi) {
    unsigned r;
    asm("v_cvt_pk_bf16_f32 %0, %1, %2" : "=v"(r) : "v"(lo), "v"(hi));
    return r;
}
__device__ __forceinline__ void gl2lds16(const void* g, void* l) {
    __builtin_amdgcn_global_load_lds((const __attribute__((address_space(1))) void*)g,
                                     (__attribute__((address_space(3))) void*)l, 16, 0, 0);
}

// ---------------- prep: pack inputs to bf16 + transpose all 3 weights ----------------
__global__ __launch_bounds__(256) void prep(
    const float* __restrict__ memory, const float* __restrict__ hidden,
    const float* __restrict__ pos, const float* __restrict__ Wqkv,
    const float* __restrict__ Wpe, const float* __restrict__ Wout,
    u16* __restrict__ MH, u16* __restrict__ PEA,
    u16* __restrict__ WQKVT, u16* __restrict__ WPET, u16* __restrict__ WOUTT)
{
    __shared__ float ls[64][65];
    const int b = blockIdx.x, t = threadIdx.x;
    if (b < 8192) {
        size_t e = ((size_t)b * 256 + t) * 4;
        const size_t HALF = (size_t)KLEN * DM;
        f32x4 v; u16* dst;
        if (e < HALF) {
            size_t row = e >> 10, col = e & 1023;
            const float* src = (row < MLEN) ? (memory + row * DM) : (hidden + (row - MLEN) * DM);
            v = *(const f32x4*)(src + col);
            dst = MH + e;
        } else {
            size_t e2 = e - HALF;
            v = *(const f32x4*)(pos + e2);
            dst = PEA + e2;
        }
        u16x4 o;
        #pragma unroll
        for (int c = 0; c < 4; ++c) o[c] = f2bf(v[c]);
        *(u16x4*)dst = o;
        return;
    }
    int tb = b - 8192;
    const float* src; u16* dst; int N, bx, by;
    if (tb < 768)       { src = Wqkv; dst = WQKVT; N = 3 * DM; bx = tb % 48; by = tb / 48; }
    else if (tb < 1024) { int i = tb - 768;  src = Wpe;  dst = WPET;  N = DM; bx = i & 15; by = i >> 4; }
    else                { int i = tb - 1024; src = Wout; dst = WOUTT; N = DM; bx = i & 15; by = i >> 4; }
    const int n0 = bx * 64, k0 = by * 64;
    const int c = t & 63, rg = t >> 6;
    #pragma unroll
    for (int p = 0; p < 16; ++p) {
        int r = p * 4 + rg;
        ls[r][c] = src[(size_t)(k0 + r) * N + n0 + c];
    }
    __syncthreads();
    #pragma unroll
    for (int p = 0; p < 16; ++p) {
        int r = p * 4 + rg;
        dst[(size_t)(n0 + r) * DM + k0 + c] = f2bf(ls[c][r]);
    }
}

// ---------------- fused QKV + PE GEMM: 2-phase double-buffered (T3 minimum recipe) ----------------
// Loop: STAGE(buf^1, t+1) issued BEFORE compute(t); one vmcnt(0)+barrier per tile.
// LDS 64 KB (2 bufs x [A|B] 128x64 u16), chunk^=(row&7) swizzle (round-14, conflict-free).
__global__ __launch_bounds__(256, 2) void gemm_qkvpe(
    const u16* __restrict__ MH, const u16* __restrict__ PEA,
    const u16* __restrict__ WQKVT, const u16* __restrict__ WPET,
    const float* __restrict__ u, const float* __restrict__ vv,
    u16* __restrict__ QHAT, u16* __restrict__ KHAT, u16* __restrict__ VB)
{
    __shared__ __align__(16) u16 ls[2][2 * 8192];   // 64 KB
    const int b = blockIdx.x;
    int row0, col0, region; const u16 *A, *B;
    if (b < 512)      { row0 = (b >> 4) * 128; col0 = 1024 + (b & 15) * 128; A = MH; B = WQKVT;
                        region = (col0 < 2048) ? 1 : 2; }
    else if (b < 640) { int i = b - 512; row0 = 2048 + (i >> 3) * 128; col0 = (i & 7) * 128;
                        A = MH; B = WQKVT; region = 0; }
    else              { int i = b - 640; row0 = (i >> 3) * 128; col0 = (i & 7) * 128;
                        A = PEA; B = WPET; region = 3; }
    const int tid = threadIdx.x, wave = tid >> 6, lane = tid & 63;
    const int blk = lane >> 4, ln = lane & 15;
    const int wr = (wave >> 1) << 6, wc = (wave & 1) << 6;
    const int rstage = lane >> 3;
    const int cswz = ((lane & 7) ^ rstage) * 8;   // source col, chunk ^= (row&7)

    auto stage = [&](int buf, int k0) {
        #pragma unroll
        for (int t = 0; t < 4; ++t) {
            int chunk = wave * 4 + t;
            int r = chunk * 8 + rstage;
            gl2lds16(A + (size_t)(row0 + r) * DM + k0 + cswz, &ls[buf][chunk * 512]);
            gl2lds16(B + (size_t)(col0 + r) * DM + k0 + cswz, &ls[buf][8192 + chunk * 512]);
        }
    };

    f32x4 acc[4][4];
    #pragma unroll
    for (int i = 0; i < 4; ++i)
        #pragma unroll
        for (int j = 0; j < 4; ++j) acc[i][j] = f32x4{0.f, 0.f, 0.f, 0.f};

    stage(0, 0);
    asm volatile("s_waitcnt vmcnt(0)" ::: "memory");
    __syncthreads();
    int cur = 0;
    const int NSTEP = 16;
    for (int t = 0; t < NSTEP; ++t) {
        if (t + 1 < NSTEP) stage(cur ^ 1, (t + 1) * 64);   // prefetch next tile
        const u16* la = ls[cur];
        const u16* lb = ls[cur] + 8192;
        #pragma unroll
        for (int kk = 0; kk < 2; ++kk) {
            bf16x8 af[4], bfr[4];
            #pragma unroll
            for (int i = 0; i < 4; ++i) {
                int ro = wr + i * 16 + ln;
                af[i] = *(const bf16x8*)(la + ro * 64 + (((kk * 4 + blk) ^ (ro & 7)) * 8));
            }
            #pragma unroll
            for (int j = 0; j < 4; ++j) {
                int ro = wc + j * 16 + ln;
                bfr[j] = *(const bf16x8*)(lb + ro * 64 + (((kk * 4 + blk) ^ (ro & 7)) * 8));
            }
            #pragma unroll
            for (int i = 0; i < 4; ++i)
                #pragma unroll
                for (int j = 0; j < 4; ++j)
                    acc[i][j] = __builtin_amdgcn_mfma_f32_16x16x32_bf16(af[i], bfr[j], acc[i][j], 0, 0, 0);
        }
        asm volatile("s_waitcnt vmcnt(0)" ::: "memory");   // next tile landed
        __syncthreads();
        cur ^= 1;
    }

    #pragma unroll
    for (int i = 0; i < 4; ++i)
        #pragma unroll
        for (int j = 0; j < 4; ++j)
            #pragma unroll
            for (int r = 0; r < 4; ++r) {
                int row = row0 + wr + i * 16 + blk * 4 + r;
                int col = col0 + wc + j * 16 + ln;
                float val = acc[i][j][r];
                if (region == 0) {            // Q -> QHAT (both halves, u/v + exp2-scale)
                    int q = row - MLEN, h = col >> 6;
                    size_t base = ((size_t)h * QLEN + q) * 128 + (col & 63);
                    QHAT[base]      = f2bf((val + u[col]) * QSCALE);
                    QHAT[base + 64] = f2bf((val + vv[col]) * QSCALE);
                } else if (region == 1) {     // K -> KHAT[0:64]
                    int c = col - 1024, h = c >> 6;
                    KHAT[((size_t)h * KLEN + row) * 128 + (c & 63)] = f2bf(val);
                } else if (region == 2) {     // V -> VB (row-major)
                    VB[(size_t)row * DM + (col - 2048)] = f2bf(val);
                } else {                      // pe -> KHAT[64:128]
                    int h = col >> 6;
                    KHAT[((size_t)h * KLEN + row) * 128 + 64 + (col & 63)] = f2bf(val);
                }
            }
}

// ---------------- pack VT[h][d][k] = VB[k][h*64+d] ----------------
__global__ __launch_bounds__(256) void pack_vt(const u16* __restrict__ VB, u16* __restrict__ VT)
{
    __shared__ float ls[64][65];
    const int kt = blockIdx.x, h = blockIdx.y;
    const int t = threadIdx.x, c = t & 63, rg = t >> 6;
    #pragma unroll
    for (int p = 0; p < 16; ++p) {
        int r = p * 4 + rg;
        ls[r][c] = bf2f(VB[(size_t)(kt * 64 + r) * DM + h * 64 + c]);
    }
    __syncthreads();
    #pragma unroll
    for (int p = 0; p < 16; ++p) {
        int d = p * 4 + rg;
        VT[((size_t)h * DHEAD + d) * KLEN + kt * 64 + c] = f2bf(ls[c][d]);
    }
}

// ---------------- fused flash attention: key-split x4, V reg-staged + T5 setprio ----------------
__global__ __launch_bounds__(256, 4) void attn_fused(
    const u16* __restrict__ QHAT, const u16* __restrict__ KHAT,
    const u16* __restrict__ VT, u16* __restrict__ OPb, float* __restrict__ ML)
{
    // u16 units: K 2x4096 [0,8192), V 2x2560 [8192,13312), P 4x1280 [13312,18432)
    __shared__ __align__(16) u16 smem[18432];
    const int b = blockIdx.x;
    const int h  = ((b & 7) << 1) | ((b >> 3) & 1);
    const int ks = b >> 8;                            // key-quarter 0..3
    const int qb = (((b >> 4) & 15) + 4 * ks) & 15;   // scrambled for per-CU balance
    const int tid = threadIdx.x;
    const int wave = tid >> 6, lane = tid & 63;
    const int l31 = lane & 31, hi = lane >> 5;
    const int qrow0 = qb * 128 + wave * 32;
    u16* pb = smem + 13312 + wave * 1280;
    const int px = (l31 >> 3) & 3;

    const u16* khp = KHAT + (size_t)h * KLEN * 128;
    const u16* vhp = VT + (size_t)h * DHEAD * KLEN;

    const int nt = qb + 17;
    const int kbase = ks * nt * 32;
    const int vd = tid >> 2, vc = tid & 3;            // V staging geometry
    const int vslot = vc ^ ((vd >> 3) & 3);

    auto stage_load = [&](int buf, int kt) -> bf16x8 {
        const int k0 = kbase + kt * 32;
        u16* Kb = smem + buf * 4096;
        #pragma unroll
        for (int i = 0; i < 2; ++i) {
            int c = i * 256 + tid;
            int row = c >> 4, cgl = c & 15;
            int cs = cgl ^ (row & 15);
            gl2lds16(khp + ((size_t)(k0 + row) << 7) + cs * 8,
                     Kb + (size_t)(i * 256 + (tid & ~63)) * 8);
        }
        return *(const bf16x8*)(vhp + (size_t)vd * KLEN + k0 + vc * 8);
    };
    auto stage_write = [&](int buf, bf16x8 vr) {
        *(bf16x8*)(smem + 8192 + buf * 2560 + vd * 40 + vslot * 8) = vr;
    };

    bf16x8 qf[8];
    {
        const u16* qbase = QHAT + ((size_t)h * QLEN + qrow0 + l31) * 128 + hi * 8;
        #pragma unroll
        for (int kd = 0; kd < 8; ++kd) qf[kd] = *(const bf16x8*)(qbase + kd * 16);
    }

    f32x16 oacc[2];
    #pragma unroll
    for (int dg = 0; dg < 2; ++dg)
        #pragma unroll
        for (int r = 0; r < 16; ++r) oacc[dg][r] = 0.f;
    float mi = -1e30f, li = 0.f;

    const int qlim = qrow0 + 31 + MLEN;
    const int qsel = qrow0 + l31 + MLEN;

    bf16x8 vreg = stage_load(0, 0);
    asm volatile("s_waitcnt vmcnt(0)" ::: "memory");
    stage_write(0, vreg);
    __syncthreads();

    int cur = 0;
    for (int kt = 0; kt < nt; ++kt) {
        const int k0 = kbase + kt * 32;
        const bool pre = (kt + 1 < nt);
        if (pre) vreg = stage_load(cur ^ 1, kt + 1);

        if (k0 <= qlim) {
            // ---- QK^T (swapped): S^T[key][q], 8 chained MFMAs over d=128 ----
            f32x16 sacc;
            #pragma unroll
            for (int r = 0; r < 16; ++r) sacc[r] = 0.f;
            const u16* kb = smem + cur * 4096;
            const int rx = l31 & 15;
            __builtin_amdgcn_s_setprio(1);
            #pragma unroll
            for (int kd = 0; kd < 8; ++kd) {
                int cd = (kd * 2 + hi) ^ rx;
                bf16x8 kf = *(const bf16x8*)(kb + l31 * 128 + cd * 8);
                sacc = __builtin_amdgcn_mfma_f32_32x32x16_bf16(kf, qf[kd], sacc, 0, 0, 0);
            }
            __builtin_amdgcn_s_setprio(0);
            // ---- causal mask (rare tiles) ----
            if (k0 + 31 > qrow0 + MLEN) {
                const int keyb = k0 + 4 * hi;
                #pragma unroll
                for (int r = 0; r < 16; ++r) {
                    int key = keyb + (r & 3) + 8 * (r >> 2);
                    if (key > qsel) sacc[r] = -1e30f;
                }
            }
            // ---- in-register online softmax (exp2 domain, tree reductions) ----
            float mt;
            {
                f32x4 m4;
                #pragma unroll
                for (int r = 0; r < 4; ++r)
                    m4[r] = fmaxf(fmaxf(sacc[r], sacc[4 + r]), fmaxf(sacc[8 + r], sacc[12 + r]));
                mt = fmaxf(fmaxf(m4[0], m4[1]), fmaxf(m4[2], m4[3]));
            }
            mt = fmaxf(mt, __shfl_xor(mt, 32, 64));
            if (!__all(mt <= mi + 8.f)) {        // T13 defer-rescale, THR=8
                float mn = fmaxf(mi, mt);
                float corr = exp2_fast(mi - mn);
                mi = mn;
                li *= corr;
                #pragma unroll
                for (int dg = 0; dg < 2; ++dg)
                    #pragma unroll
                    for (int r = 0; r < 16; ++r) oacc[dg][r] *= corr;
            }
            #pragma unroll
            for (int r = 0; r < 16; ++r) sacc[r] = exp2_fast(sacc[r] - mi);
            float rs;
            {
                f32x4 s4;
                #pragma unroll
                for (int r = 0; r < 4; ++r)
                    s4[r] = (sacc[r] + sacc[4 + r]) + (sacc[8 + r] + sacc[12 + r]);
                rs = (s4[0] + s4[1]) + (s4[2] + s4[3]);
            }
            li += rs + __shfl_xor(rs, 32, 64);
            // ---- P -> LDS, 16B-chunk XOR swizzle ----
            {
                unsigned* pd = (unsigned*)(pb + (size_t)l31 * 40);
                #pragma unroll
                for (int b2 = 0; b2 < 4; ++b2)
                    #pragma unroll
                    for (int c = 0; c < 2; ++c)
                        pd[(b2 ^ px) * 4 + 2 * hi + c] =
                            cvtpk_bf16(sacc[4 * b2 + 2 * c], sacc[4 * b2 + 2 * c + 1]);
            }
            // ---- PV from padded V buffer ----
            __builtin_amdgcn_s_setprio(1);
            #pragma unroll
            for (int kkl = 0; kkl < 2; ++kkl) {
                bf16x8 pf = *(const bf16x8*)(pb + (size_t)l31 * 40 + ((kkl * 2 + hi) ^ px) * 8);
                #pragma unroll
                for (int dg = 0; dg < 2; ++dg) {
                    int vrow = dg * 32 + l31;
                    int cd = (kkl * 2 + hi) ^ ((l31 >> 3) & 3);
                    bf16x8 vf = *(const bf16x8*)(smem + 8192 + cur * 2560 + vrow * 40 + cd * 8);
                    oacc[dg] = __builtin_amdgcn_mfma_f32_32x32x16_bf16(vf, pf, oacc[dg], 0, 0, 0);
                }
            }
            __builtin_amdgcn_s_setprio(0);
        }
        asm volatile("s_waitcnt vmcnt(0)" ::: "memory");
        if (pre) stage_write(cur ^ 1, vreg);
        __syncthreads();
        cur ^= 1;
    }

    // ---- write partial (m, l, O-bf16) ----
    const int q = qrow0 + l31;
    unsigned* op32 = (unsigned*)(OPb + (((size_t)ks * QLEN + q) * NHEAD + h) * 64);
    #pragma unroll
    for (int dg = 0; dg < 2; ++dg) {
        union { f32x16 v; float f[16]; } oo;
        oo.v = oacc[dg];
        #pragma unroll
        for (int b2 = 0; b2 < 4; ++b2)
            #pragma unroll
            for (int c = 0; c < 2; ++c)
                op32[(dg * 32 + 8 * b2 + 4 * hi) / 2 + c] =
                    cvtpk_bf16(oo.f[4 * b2 + 2 * c], oo.f[4 * b2 + 2 * c + 1]);
    }
    if (!hi) {
        float* ml = ML + (((size_t)ks * QLEN + q) * NHEAD + h) * 2;
        ml[0] = mi; ml[1] = li;
    }
}

// ---------------- combine the 4 key-split partials -> AVB bf16 (exp2 domain) ----------------
__global__ __launch_bounds__(256) void attn_combine(
    const u16* __restrict__ OPb, const float* __restrict__ ML, u16* __restrict__ AVB)
{
    int idx = blockIdx.x * 256 + threadIdx.x;
    int d8 = (idx & 7) * 8;
    int h  = (idx >> 3) & 15;
    int q  = idx >> 7;
    float m[4], l[4], mf = -1e30f;
    #pragma unroll
    for (int ks = 0; ks < 4; ++ks) {
        const float* ml = ML + (((size_t)ks * QLEN + q) * NHEAD + h) * 2;
        m[ks] = ml[0]; l[ks] = ml[1];
        mf = fmaxf(mf, m[ks]);
    }
    float lsum = 0.f;
    float a[4];
    #pragma unroll
    for (int ks = 0; ks < 4; ++ks) {
        a[ks] = exp2_fast(m[ks] - mf);
        lsum += a[ks] * l[ks];
    }
    float inv = 1.f / lsum;
    float acc[8];
    #pragma unroll
    for (int j = 0; j < 8; ++j) acc[j] = 0.f;
    #pragma unroll
    for (int ks = 0; ks < 4; ++ks) {
        float w = a[ks] * inv;
        const u16* src = OPb + (((size_t)ks * QLEN + q) * NHEAD + h) * 64 + d8;
        u16x4 x0 = *(const u16x4*)(src);
        u16x4 x1 = *(const u16x4*)(src + 4);
        #pragma unroll
        for (int j = 0; j < 4; ++j) { acc[j] += w * bf2f(x0[j]); acc[4 + j] += w * bf2f(x1[j]); }
    }
    unsigned* A32 = (unsigned*)AVB;
    size_t base = ((size_t)q * DM + h * 64 + d8) >> 1;
    #pragma unroll
    for (int j = 0; j < 4; ++j)
        A32[base + j] = cvtpk_bf16(acc[2 * j], acc[2 * j + 1]);
}

// ---------------- out GEMM, split-K x2: 2-phase double-buffered ----------------
__global__ __launch_bounds__(256, 2) void gemm_out(
    const u16* __restrict__ A, const u16* __restrict__ Bt, float* __restrict__ RES)
{
    __shared__ __align__(16) u16 ls[2][2 * 8192];   // 64 KB
    const int b = blockIdx.x;
    const int tile = b >> 1, kh = b & 1;
    const int row0 = (tile >> 3) * 128, col0 = (tile & 7) * 128;
    const int tid = threadIdx.x, wave = tid >> 6, lane = tid & 63;
    const int blk = lane >> 4, ln = lane & 15;
    const int wr = (wave >> 1) << 6, wc = (wave & 1) << 6;
    const int rstage = lane >> 3;
    const int cswz = ((lane & 7) ^ rstage) * 8;
    const int kbase = kh * 512;

    auto stage = [&](int buf, int k0) {
        #pragma unroll
        for (int t = 0; t < 4; ++t) {
            int chunk = wave * 4 + t;
            int r = chunk * 8 + rstage;
            gl2lds16(A  + (size_t)(row0 + r) * DM + k0 + cswz, &ls[buf][chunk * 512]);
            gl2lds16(Bt + (size_t)(col0 + r) * DM + k0 + cswz, &ls[buf][8192 + chunk * 512]);
        }
    };

    f32x4 acc[4][4];
    #pragma unroll
    for (int i = 0; i < 4; ++i)
        #pragma unroll
        for (int j = 0; j < 4; ++j) acc[i][j] = f32x4{0.f, 0.f, 0.f, 0.f};

    stage(0, kbase);
    asm volatile("s_waitcnt vmcnt(0)" ::: "memory");
    __syncthreads();
    int cur = 0;
    const int NSTEP = 8;
    for (int t = 0; t < NSTEP; ++t) {
        if (t + 1 < NSTEP) stage(cur ^ 1, kbase + (t + 1) * 64);
        const u16* la = ls[cur];
        const u16* lb = ls[cur] + 8192;
        #pragma unroll
        for (int kk = 0; kk < 2; ++kk) {
            bf16x8 af[4], bfr[4];
            #pragma unroll
            for (int i = 0; i < 4; ++i) {
                int ro = wr + i * 16 + ln;
                af[i] = *(const bf16x8*)(la + ro * 64 + (((kk * 4 + blk) ^ (ro & 7)) * 8));
            }
            #pragma unroll
            for (int j = 0; j < 4; ++j) {
                int ro = wc + j * 16 + ln;
                bfr[j] = *(const bf16x8*)(lb + ro * 64 + (((kk * 4 + blk) ^ (ro & 7)) * 8));
            }
            #pragma unroll
            for (int i = 0; i < 4; ++i)
                #pragma unroll
                for (int j = 0; j < 4; ++j)
                    acc[i][j] = __builtin_amdgcn_mfma_f32_16x16x32_bf16(af[i], bfr[j], acc[i][j], 0, 0, 0);
        }
        asm volatile("s_waitcnt vmcnt(0)" ::: "memory");
        __syncthreads();
        cur ^= 1;
    }
    float* C = RES + (size_t)kh * QLEN * DM;
    #pragma unroll
    for (int i = 0; i < 4; ++i)
        #pragma unroll
        for (int j = 0; j < 4; ++j)
            #pragma unroll
            for (int r = 0; r < 4; ++r) {
                int row = row0 + wr + i * 16 + blk * 4 + r;
                int col = col0 + wc + j * 16 + ln;
                C[(size_t)row * DM + col] = acc[i][j][r];
            }
}

// ---------------- layernorm over last dim: out = LN(hidden + RES0 + RES1) ----------------
__global__ __launch_bounds__(256) void ln_kernel(
    const float* __restrict__ hidden, const float* __restrict__ RES, float* __restrict__ out)
{
    const int row = blockIdx.x, t = threadIdx.x;
    const int wave = t >> 6, lane = t & 63;
    __shared__ float ws[8];
    f32x4 a = ((const f32x4*)(hidden + (size_t)row * DM))[t];
    f32x4 r0 = ((const f32x4*)(RES + (size_t)row * DM))[t];
    f32x4 r1 = ((const f32x4*)(RES + (size_t)(QLEN + row) * DM))[t];
    f32x4 v;
    #pragma unroll
    for (int c = 0; c < 4; ++c) v[c] = a[c] + r0[c] + r1[c];
    float s = v[0] + v[1] + v[2] + v[3];
    float s2 = v[0] * v[0] + v[1] * v[1] + v[2] * v[2] + v[3] * v[3];
    #pragma unroll
    for (int off = 1; off < 64; off <<= 1) {
        s += __shfl_xor(s, off, 64);
        s2 += __shfl_xor(s2, off, 64);
    }
    if (lane == 0) { ws[wave] = s; ws[4 + wave] = s2; }
    __syncthreads();
    float ts = ws[0] + ws[1] + ws[2] + ws[3];
    float ts2 = ws[4] + ws[5] + ws[6] + ws[7];
    float mu = ts * (1.f / DM);
    float var = ts2 * (1.f / DM) - mu * mu;
    float rsq = rsqrtf(var + 1e-5f);
    f32x4 o;
    #pragma unroll
    for (int c = 0; c < 4; ++c) o[c] = (v[c] - mu) * rsq;
    ((f32x4*)(out + (size_t)row * DM))[t] = o;
}

extern "C" void kernel_launch(void* const* d_in, const int* in_sizes, int n_in,
                              void* d_out, int out_size, void* d_ws, size_t ws_size,
                              hipStream_t stream)
{
    const float* hidden = (const float*)d_in[0];
    const float* pos    = (const float*)d_in[1];
    const float* u      = (const float*)d_in[2];
    const float* vv     = (const float*)d_in[3];
    const float* memory = (const float*)d_in[5];
    const float* Wqkv   = (const float*)d_in[6];
    const float* Wpe    = (const float*)d_in[7];
    const float* Wout   = (const float*)d_in[8];
    float* out = (float*)d_out;

    char* w = (char*)d_ws;
    auto alloc = [&](size_t bytes) {
        void* p = (void*)w;
        w += (bytes + 255) & ~(size_t)255;
        return p;
    };
    // OPb (16.8 MB bf16) + ML (1 MB) alias the front pool (MH, PEA, WQKVT: 22 MB),
    // all dead before attn_fused runs.
    u16* MH    = (u16*)alloc((size_t)KLEN * DM * 2);
    u16* PEA   = (u16*)alloc((size_t)KLEN * DM * 2);
    u16* WQKVT = (u16*)alloc((size_t)3 * DM * DM * 2);
    u16* WPET  = (u16*)alloc((size_t)DM * DM * 2);
    u16* VB    = (u16*)alloc((size_t)KLEN * DM * 2);
    u16* QHAT  = (u16*)alloc((size_t)NHEAD * QLEN * 128 * 2);
    u16* KHAT  = (u16*)alloc((size_t)NHEAD * KLEN * 128 * 2);
    u16* VTb   = (u16*)alloc((size_t)NHEAD * DHEAD * KLEN * 2);
    u16* AVB   = (u16*)alloc((size_t)QLEN * DM * 2);
    float* RES = (float*)alloc((size_t)2 * QLEN * DM * 4);
    u16* WOUTT = (u16*)alloc((size_t)DM * DM * 2);
    u16* OPb   = (u16*)d_ws;
    float* ML  = (float*)((char*)d_ws + (size_t)4 * QLEN * NHEAD * 64 * 2);

    prep<<<8192 + 1280, 256, 0, stream>>>(memory, hidden, pos, Wqkv, Wpe, Wout,
                                          MH, PEA, WQKVT, WPET, WOUTT);
    gemm_qkvpe<<<896, 256, 0, stream>>>(MH, PEA, WQKVT, WPET, u, vv, QHAT, KHAT, VB);
    pack_vt<<<dim3(KLEN / 64, NHEAD), 256, 0, stream>>>(VB, VTb);
    attn_fused<<<dim3(1024), 256, 0, stream>>>(QHAT, KHAT, VTb, OPb, ML);
    attn_combine<<<dim3(QLEN * NHEAD * 8 / 256), 256, 0, stream>>>(OPb, ML, AVB);
    gemm_out<<<256, 256, 0, stream>>>(AVB, WOUTT, RES);
    ln_kernel<<<QLEN, 256, 0, stream>>>(hidden, RES, out);
}

// Round 16
// 160.604 us; speedup vs baseline: 1.0103x; 1.0103x over previous
//
#include <hip/hip_runtime.h>

typedef __attribute__((ext_vector_type(4))) float f32x4;
typedef __attribute__((ext_vector_type(16))) float f32x16;
typedef __attribute__((ext_vector_type(8))) short bf16x8;
typedef __attribute__((ext_vector_type(4))) unsigned short u16x4;
typedef unsigned short u16;

#define DM 1024
#define NHEAD 16
#define DHEAD 64
#define QLEN 2048
#define MLEN 2048
#define KLEN 4096
#define QSCALE 0.18033688011112042f   // 0.125 * log2(e): softmax in exp2 domain

__device__ __forceinline__ float bf2f(u16 u) {
    unsigned i = ((unsigned)u) << 16; float f; __builtin_memcpy(&f, &i, 4); return f;
}
__device__ __forceinline__ u16 f2bf(float f) {
    unsigned i; __builtin_memcpy(&i, &f, 4);
    unsigned r = i + 0x7fffu + ((i >> 16) & 1u);
    return (u16)(r >> 16);
}
__device__ __forceinline__ float exp2_fast(float x) {
#if __has_builtin(__builtin_amdgcn_exp2f)
    return __builtin_amdgcn_exp2f(x);
#else
    return exp2f(x);
#endif
}
__device__ __forceinline__ unsigned cvtpk_bf16(float lo, float hi) {
    unsigned r;
    asm("v_cvt_pk_bf16_f32 %0, %1, %2" : "=v"(r) : "v"(lo), "v"(hi));
    return r;
}
__device__ __forceinline__ void gl2lds16(const void* g, void* l) {
    __builtin_amdgcn_global_load_lds((const __attribute__((address_space(1))) void*)g,
                                     (__attribute__((address_space(3))) void*)l, 16, 0, 0);
}

// ---------------- prep: pack inputs to bf16 + transpose all 3 weights ----------------
__global__ __launch_bounds__(256) void prep(
    const float* __restrict__ memory, const float* __restrict__ hidden,
    const float* __restrict__ pos, const float* __restrict__ Wqkv,
    const float* __restrict__ Wpe, const float* __restrict__ Wout,
    u16* __restrict__ MH, u16* __restrict__ PEA,
    u16* __restrict__ WQKVT, u16* __restrict__ WPET, u16* __restrict__ WOUTT)
{
    __shared__ float ls[64][65];
    const int b = blockIdx.x, t = threadIdx.x;
    if (b < 8192) {
        size_t e = ((size_t)b * 256 + t) * 4;
        const size_t HALF = (size_t)KLEN * DM;
        f32x4 v; u16* dst;
        if (e < HALF) {
            size_t row = e >> 10, col = e & 1023;
            const float* src = (row < MLEN) ? (memory + row * DM) : (hidden + (row - MLEN) * DM);
            v = *(const f32x4*)(src + col);
            dst = MH + e;
        } else {
            size_t e2 = e - HALF;
            v = *(const f32x4*)(pos + e2);
            dst = PEA + e2;
        }
        u16x4 o;
        #pragma unroll
        for (int c = 0; c < 4; ++c) o[c] = f2bf(v[c]);
        *(u16x4*)dst = o;
        return;
    }
    int tb = b - 8192;
    const float* src; u16* dst; int N, bx, by;
    if (tb < 768)       { src = Wqkv; dst = WQKVT; N = 3 * DM; bx = tb % 48; by = tb / 48; }
    else if (tb < 1024) { int i = tb - 768;  src = Wpe;  dst = WPET;  N = DM; bx = i & 15; by = i >> 4; }
    else                { int i = tb - 1024; src = Wout; dst = WOUTT; N = DM; bx = i & 15; by = i >> 4; }
    const int n0 = bx * 64, k0 = by * 64;
    const int c = t & 63, rg = t >> 6;
    #pragma unroll
    for (int p = 0; p < 16; ++p) {
        int r = p * 4 + rg;
        ls[r][c] = src[(size_t)(k0 + r) * N + n0 + c];
    }
    __syncthreads();
    #pragma unroll
    for (int p = 0; p < 16; ++p) {
        int r = p * 4 + rg;
        dst[(size_t)(n0 + r) * DM + k0 + c] = f2bf(ls[c][r]);
    }
}

// ---------------- fused QKV + PE GEMM (round-14: 1-phase, swizzled, 3 blocks/CU) ----------------
__global__ __launch_bounds__(256, 3) void gemm_qkvpe(
    const u16* __restrict__ MH, const u16* __restrict__ PEA,
    const u16* __restrict__ WQKVT, const u16* __restrict__ WPET,
    const float* __restrict__ u, const float* __restrict__ vv,
    u16* __restrict__ QHAT, u16* __restrict__ KHAT, u16* __restrict__ VB)
{
    __shared__ u16 lsA[128 * 64];
    __shared__ u16 lsB[128 * 64];
    const int b = blockIdx.x;
    int row0, col0, region; const u16 *A, *B;
    if (b < 512)      { row0 = (b >> 4) * 128; col0 = 1024 + (b & 15) * 128; A = MH; B = WQKVT;
                        region = (col0 < 2048) ? 1 : 2; }
    else if (b < 640) { int i = b - 512; row0 = 2048 + (i >> 3) * 128; col0 = (i & 7) * 128;
                        A = MH; B = WQKVT; region = 0; }
    else              { int i = b - 640; row0 = (i >> 3) * 128; col0 = (i & 7) * 128;
                        A = PEA; B = WPET; region = 3; }
    const int tid = threadIdx.x, wave = tid >> 6, lane = tid & 63;
    const int blk = lane >> 4, ln = lane & 15;
    const int wr = (wave >> 1) << 6, wc = (wave & 1) << 6;
    const int rstage = lane >> 3;
    const int cswz = ((lane & 7) ^ rstage) * 8;   // source col, chunk ^= (row&7)

    f32x4 acc[4][4];
    #pragma unroll
    for (int i = 0; i < 4; ++i)
        #pragma unroll
        for (int j = 0; j < 4; ++j) acc[i][j] = f32x4{0.f, 0.f, 0.f, 0.f};

    for (int k0 = 0; k0 < DM; k0 += 64) {
        #pragma unroll
        for (int t = 0; t < 4; ++t) {
            int chunk = wave * 4 + t;
            int r = chunk * 8 + rstage;
            gl2lds16(A + (size_t)(row0 + r) * DM + k0 + cswz, lsA + chunk * 512);
            gl2lds16(B + (size_t)(col0 + r) * DM + k0 + cswz, lsB + chunk * 512);
        }
        __syncthreads();
        #pragma unroll
        for (int kk = 0; kk < 2; ++kk) {
            bf16x8 af[4], bfr[4];
            #pragma unroll
            for (int i = 0; i < 4; ++i) {
                int ro = wr + i * 16 + ln;
                af[i] = *(const bf16x8*)(lsA + ro * 64 + (((kk * 4 + blk) ^ (ro & 7)) * 8));
            }
            #pragma unroll
            for (int j = 0; j < 4; ++j) {
                int ro = wc + j * 16 + ln;
                bfr[j] = *(const bf16x8*)(lsB + ro * 64 + (((kk * 4 + blk) ^ (ro & 7)) * 8));
            }
            #pragma unroll
            for (int i = 0; i < 4; ++i)
                #pragma unroll
                for (int j = 0; j < 4; ++j)
                    acc[i][j] = __builtin_amdgcn_mfma_f32_16x16x32_bf16(af[i], bfr[j], acc[i][j], 0, 0, 0);
        }
        __syncthreads();
    }
    #pragma unroll
    for (int i = 0; i < 4; ++i)
        #pragma unroll
        for (int j = 0; j < 4; ++j)
            #pragma unroll
            for (int r = 0; r < 4; ++r) {
                int row = row0 + wr + i * 16 + blk * 4 + r;
                int col = col0 + wc + j * 16 + ln;
                float val = acc[i][j][r];
                if (region == 0) {            // Q -> QHAT (both halves, u/v + exp2-scale)
                    int q = row - MLEN, h = col >> 6;
                    size_t base = ((size_t)h * QLEN + q) * 128 + (col & 63);
                    QHAT[base]      = f2bf((val + u[col]) * QSCALE);
                    QHAT[base + 64] = f2bf((val + vv[col]) * QSCALE);
                } else if (region == 1) {     // K -> KHAT[0:64]
                    int c = col - 1024, h = c >> 6;
                    KHAT[((size_t)h * KLEN + row) * 128 + (c & 63)] = f2bf(val);
                } else if (region == 2) {     // V -> VB (row-major)
                    VB[(size_t)row * DM + (col - 2048)] = f2bf(val);
                } else {                      // pe -> KHAT[64:128]
                    int h = col >> 6;
                    KHAT[((size_t)h * KLEN + row) * 128 + 64 + (col & 63)] = f2bf(val);
                }
            }
}

// ---------------- pack VT[h][d][k] = VB[k][h*64+d] ----------------
__global__ __launch_bounds__(256) void pack_vt(const u16* __restrict__ VB, u16* __restrict__ VT)
{
    __shared__ float ls[64][65];
    const int kt = blockIdx.x, h = blockIdx.y;
    const int t = threadIdx.x, c = t & 63, rg = t >> 6;
    #pragma unroll
    for (int p = 0; p < 16; ++p) {
        int r = p * 4 + rg;
        ls[r][c] = bf2f(VB[(size_t)(kt * 64 + r) * DM + h * 64 + c]);
    }
    __syncthreads();
    #pragma unroll
    for (int p = 0; p < 16; ++p) {
        int d = p * 4 + rg;
        VT[((size_t)h * DHEAD + d) * KLEN + kt * 64 + c] = f2bf(ls[c][d]);
    }
}

// ---------------- fused flash attention: key-split x4, V reg-staged + T5 setprio ----------------
__global__ __launch_bounds__(256, 4) void attn_fused(
    const u16* __restrict__ QHAT, const u16* __restrict__ KHAT,
    const u16* __restrict__ VT, u16* __restrict__ OPb, float* __restrict__ ML)
{
    // u16 units: K 2x4096 [0,8192), V 2x2560 [8192,13312), P 4x1280 [13312,18432)
    __shared__ __align__(16) u16 smem[18432];
    const int b = blockIdx.x;
    const int h  = ((b & 7) << 1) | ((b >> 3) & 1);
    const int ks = b >> 8;                            // key-quarter 0..3
    const int qb = (((b >> 4) & 15) + 4 * ks) & 15;   // scrambled for per-CU balance
    const int tid = threadIdx.x;
    const int wave = tid >> 6, lane = tid & 63;
    const int l31 = lane & 31, hi = lane >> 5;
    const int qrow0 = qb * 128 + wave * 32;
    u16* pb = smem + 13312 + wave * 1280;
    const int px = (l31 >> 3) & 3;

    const u16* khp = KHAT + (size_t)h * KLEN * 128;
    const u16* vhp = VT + (size_t)h * DHEAD * KLEN;

    const int nt = qb + 17;
    const int kbase = ks * nt * 32;
    const int vd = tid >> 2, vc = tid & 3;            // V staging geometry
    const int vslot = vc ^ ((vd >> 3) & 3);

    auto stage_load = [&](int buf, int kt) -> bf16x8 {
        const int k0 = kbase + kt * 32;
        u16* Kb = smem + buf * 4096;
        #pragma unroll
        for (int i = 0; i < 2; ++i) {
            int c = i * 256 + tid;
            int row = c >> 4, cgl = c & 15;
            int cs = cgl ^ (row & 15);
            gl2lds16(khp + ((size_t)(k0 + row) << 7) + cs * 8,
                     Kb + (size_t)(i * 256 + (tid & ~63)) * 8);
        }
        return *(const bf16x8*)(vhp + (size_t)vd * KLEN + k0 + vc * 8);
    };
    auto stage_write = [&](int buf, bf16x8 vr) {
        *(bf16x8*)(smem + 8192 + buf * 2560 + vd * 40 + vslot * 8) = vr;
    };

    bf16x8 qf[8];
    {
        const u16* qbase = QHAT + ((size_t)h * QLEN + qrow0 + l31) * 128 + hi * 8;
        #pragma unroll
        for (int kd = 0; kd < 8; ++kd) qf[kd] = *(const bf16x8*)(qbase + kd * 16);
    }

    f32x16 oacc[2];
    #pragma unroll
    for (int dg = 0; dg < 2; ++dg)
        #pragma unroll
        for (int r = 0; r < 16; ++r) oacc[dg][r] = 0.f;
    float mi = -1e30f, li = 0.f;

    const int qlim = qrow0 + 31 + MLEN;
    const int qsel = qrow0 + l31 + MLEN;

    bf16x8 vreg = stage_load(0, 0);
    asm volatile("s_waitcnt vmcnt(0)" ::: "memory");
    stage_write(0, vreg);
    __syncthreads();

    int cur = 0;
    for (int kt = 0; kt < nt; ++kt) {
        const int k0 = kbase + kt * 32;
        const bool pre = (kt + 1 < nt);
        if (pre) vreg = stage_load(cur ^ 1, kt + 1);

        if (k0 <= qlim) {
            // ---- QK^T (swapped): S^T[key][q], 8 chained MFMAs over d=128 ----
            f32x16 sacc;
            #pragma unroll
            for (int r = 0; r < 16; ++r) sacc[r] = 0.f;
            const u16* kb = smem + cur * 4096;
            const int rx = l31 & 15;
            __builtin_amdgcn_s_setprio(1);
            #pragma unroll
            for (int kd = 0; kd < 8; ++kd) {
                int cd = (kd * 2 + hi) ^ rx;
                bf16x8 kf = *(const bf16x8*)(kb + l31 * 128 + cd * 8);
                sacc = __builtin_amdgcn_mfma_f32_32x32x16_bf16(kf, qf[kd], sacc, 0, 0, 0);
            }
            __builtin_amdgcn_s_setprio(0);
            // ---- causal mask (rare tiles) ----
            if (k0 + 31 > qrow0 + MLEN) {
                const int keyb = k0 + 4 * hi;
                #pragma unroll
                for (int r = 0; r < 16; ++r) {
                    int key = keyb + (r & 3) + 8 * (r >> 2);
                    if (key > qsel) sacc[r] = -1e30f;
                }
            }
            // ---- in-register online softmax (exp2 domain, tree reductions) ----
            float mt;
            {
                f32x4 m4;
                #pragma unroll
                for (int r = 0; r < 4; ++r)
                    m4[r] = fmaxf(fmaxf(sacc[r], sacc[4 + r]), fmaxf(sacc[8 + r], sacc[12 + r]));
                mt = fmaxf(fmaxf(m4[0], m4[1]), fmaxf(m4[2], m4[3]));
            }
            mt = fmaxf(mt, __shfl_xor(mt, 32, 64));
            if (!__all(mt <= mi + 8.f)) {        // T13 defer-rescale, THR=8
                float mn = fmaxf(mi, mt);
                float corr = exp2_fast(mi - mn);
                mi = mn;
                li *= corr;
                #pragma unroll
                for (int dg = 0; dg < 2; ++dg)
                    #pragma unroll
                    for (int r = 0; r < 16; ++r) oacc[dg][r] *= corr;
            }
            #pragma unroll
            for (int r = 0; r < 16; ++r) sacc[r] = exp2_fast(sacc[r] - mi);
            float rs;
            {
                f32x4 s4;
                #pragma unroll
                for (int r = 0; r < 4; ++r)
                    s4[r] = (sacc[r] + sacc[4 + r]) + (sacc[8 + r] + sacc[12 + r]);
                rs = (s4[0] + s4[1]) + (s4[2] + s4[3]);
            }
            li += rs + __shfl_xor(rs, 32, 64);
            // ---- P -> LDS, 16B-chunk XOR swizzle ----
            {
                unsigned* pd = (unsigned*)(pb + (size_t)l31 * 40);
                #pragma unroll
                for (int b2 = 0; b2 < 4; ++b2)
                    #pragma unroll
                    for (int c = 0; c < 2; ++c)
                        pd[(b2 ^ px) * 4 + 2 * hi + c] =
                            cvtpk_bf16(sacc[4 * b2 + 2 * c], sacc[4 * b2 + 2 * c + 1]);
            }
            // ---- PV from padded V buffer ----
            __builtin_amdgcn_s_setprio(1);
            #pragma unroll
            for (int kkl = 0; kkl < 2; ++kkl) {
                bf16x8 pf = *(const bf16x8*)(pb + (size_t)l31 * 40 + ((kkl * 2 + hi) ^ px) * 8);
                #pragma unroll
                for (int dg = 0; dg < 2; ++dg) {
                    int vrow = dg * 32 + l31;
                    int cd = (kkl * 2 + hi) ^ ((l31 >> 3) & 3);
                    bf16x8 vf = *(const bf16x8*)(smem + 8192 + cur * 2560 + vrow * 40 + cd * 8);
                    oacc[dg] = __builtin_amdgcn_mfma_f32_32x32x16_bf16(vf, pf, oacc[dg], 0, 0, 0);
                }
            }
            __builtin_amdgcn_s_setprio(0);
        }
        asm volatile("s_waitcnt vmcnt(0)" ::: "memory");
        if (pre) stage_write(cur ^ 1, vreg);
        __syncthreads();
        cur ^= 1;
    }

    // ---- write partial (m, l, O-bf16) ----
    const int q = qrow0 + l31;
    unsigned* op32 = (unsigned*)(OPb + (((size_t)ks * QLEN + q) * NHEAD + h) * 64);
    #pragma unroll
    for (int dg = 0; dg < 2; ++dg) {
        union { f32x16 v; float f[16]; } oo;
        oo.v = oacc[dg];
        #pragma unroll
        for (int b2 = 0; b2 < 4; ++b2)
            #pragma unroll
            for (int c = 0; c < 2; ++c)
                op32[(dg * 32 + 8 * b2 + 4 * hi) / 2 + c] =
                    cvtpk_bf16(oo.f[4 * b2 + 2 * c], oo.f[4 * b2 + 2 * c + 1]);
    }
    if (!hi) {
        float* ml = ML + (((size_t)ks * QLEN + q) * NHEAD + h) * 2;
        ml[0] = mi; ml[1] = li;
    }
}

// ---------------- combine the 4 key-split partials -> AVB bf16 (exp2 domain) ----------------
__global__ __launch_bounds__(256) void attn_combine(
    const u16* __restrict__ OPb, const float* __restrict__ ML, u16* __restrict__ AVB)
{
    int idx = blockIdx.x * 256 + threadIdx.x;
    int d8 = (idx & 7) * 8;
    int h  = (idx >> 3) & 15;
    int q  = idx >> 7;
    float m[4], l[4], mf = -1e30f;
    #pragma unroll
    for (int ks = 0; ks < 4; ++ks) {
        const float* ml = ML + (((size_t)ks * QLEN + q) * NHEAD + h) * 2;
        m[ks] = ml[0]; l[ks] = ml[1];
        mf = fmaxf(mf, m[ks]);
    }
    float lsum = 0.f;
    float a[4];
    #pragma unroll
    for (int ks = 0; ks < 4; ++ks) {
        a[ks] = exp2_fast(m[ks] - mf);
        lsum += a[ks] * l[ks];
    }
    float inv = 1.f / lsum;
    float acc[8];
    #pragma unroll
    for (int j = 0; j < 8; ++j) acc[j] = 0.f;
    #pragma unroll
    for (int ks = 0; ks < 4; ++ks) {
        float w = a[ks] * inv;
        const u16* src = OPb + (((size_t)ks * QLEN + q) * NHEAD + h) * 64 + d8;
        u16x4 x0 = *(const u16x4*)(src);
        u16x4 x1 = *(const u16x4*)(src + 4);
        #pragma unroll
        for (int j = 0; j < 4; ++j) { acc[j] += w * bf2f(x0[j]); acc[4 + j] += w * bf2f(x1[j]); }
    }
    unsigned* A32 = (unsigned*)AVB;
    size_t base = ((size_t)q * DM + h * 64 + d8) >> 1;
    #pragma unroll
    for (int j = 0; j < 4; ++j)
        A32[base + j] = cvtpk_bf16(acc[2 * j], acc[2 * j + 1]);
}

// ---------------- out GEMM, split-K x2 (round-14: 1-phase, swizzled) ----------------
__global__ __launch_bounds__(256, 3) void gemm_out(
    const u16* __restrict__ A, const u16* __restrict__ Bt, float* __restrict__ RES)
{
    __shared__ u16 lsA[128 * 64];
    __shared__ u16 lsB[128 * 64];
    const int b = blockIdx.x;
    const int tile = b >> 1, kh = b & 1;
    const int row0 = (tile >> 3) * 128, col0 = (tile & 7) * 128;
    const int tid = threadIdx.x, wave = tid >> 6, lane = tid & 63;
    const int blk = lane >> 4, ln = lane & 15;
    const int wr = (wave >> 1) << 6, wc = (wave & 1) << 6;
    const int rstage = lane >> 3;
    const int cswz = ((lane & 7) ^ rstage) * 8;

    f32x4 acc[4][4];
    #pragma unroll
    for (int i = 0; i < 4; ++i)
        #pragma unroll
        for (int j = 0; j < 4; ++j) acc[i][j] = f32x4{0.f, 0.f, 0.f, 0.f};

    for (int k0 = kh * 512; k0 < kh * 512 + 512; k0 += 64) {
        #pragma unroll
        for (int t = 0; t < 4; ++t) {
            int chunk = wave * 4 + t;
            int r = chunk * 8 + rstage;
            gl2lds16(A  + (size_t)(row0 + r) * DM + k0 + cswz, lsA + chunk * 512);
            gl2lds16(Bt + (size_t)(col0 + r) * DM + k0 + cswz, lsB + chunk * 512);
        }
        __syncthreads();
        #pragma unroll
        for (int kk = 0; kk < 2; ++kk) {
            bf16x8 af[4], bfr[4];
            #pragma unroll
            for (int i = 0; i < 4; ++i) {
                int ro = wr + i * 16 + ln;
                af[i] = *(const bf16x8*)(lsA + ro * 64 + (((kk * 4 + blk) ^ (ro & 7)) * 8));
            }
            #pragma unroll
            for (int j = 0; j < 4; ++j) {
                int ro = wc + j * 16 + ln;
                bfr[j] = *(const bf16x8*)(lsB + ro * 64 + (((kk * 4 + blk) ^ (ro & 7)) * 8));
            }
            #pragma unroll
            for (int i = 0; i < 4; ++i)
                #pragma unroll
                for (int j = 0; j < 4; ++j)
                    acc[i][j] = __builtin_amdgcn_mfma_f32_16x16x32_bf16(af[i], bfr[j], acc[i][j], 0, 0, 0);
        }
        __syncthreads();
    }
    float* C = RES + (size_t)kh * QLEN * DM;
    #pragma unroll
    for (int i = 0; i < 4; ++i)
        #pragma unroll
        for (int j = 0; j < 4; ++j)
            #pragma unroll
            for (int r = 0; r < 4; ++r) {
                int row = row0 + wr + i * 16 + blk * 4 + r;
                int col = col0 + wc + j * 16 + ln;
                C[(size_t)row * DM + col] = acc[i][j][r];
            }
}

// ---------------- layernorm over last dim: out = LN(hidden + RES0 + RES1) ----------------
__global__ __launch_bounds__(256) void ln_kernel(
    const float* __restrict__ hidden, const float* __restrict__ RES, float* __restrict__ out)
{
    const int row = blockIdx.x, t = threadIdx.x;
    const int wave = t >> 6, lane = t & 63;
    __shared__ float ws[8];
    f32x4 a = ((const f32x4*)(hidden + (size_t)row * DM))[t];
    f32x4 r0 = ((const f32x4*)(RES + (size_t)row * DM))[t];
    f32x4 r1 = ((const f32x4*)(RES + (size_t)(QLEN + row) * DM))[t];
    f32x4 v;
    #pragma unroll
    for (int c = 0; c < 4; ++c) v[c] = a[c] + r0[c] + r1[c];
    float s = v[0] + v[1] + v[2] + v[3];
    float s2 = v[0] * v[0] + v[1] * v[1] + v[2] * v[2] + v[3] * v[3];
    #pragma unroll
    for (int off = 1; off < 64; off <<= 1) {
        s += __shfl_xor(s, off, 64);
        s2 += __shfl_xor(s2, off, 64);
    }
    if (lane == 0) { ws[wave] = s; ws[4 + wave] = s2; }
    __syncthreads();
    float ts = ws[0] + ws[1] + ws[2] + ws[3];
    float ts2 = ws[4] + ws[5] + ws[6] + ws[7];
    float mu = ts * (1.f / DM);
    float var = ts2 * (1.f / DM) - mu * mu;
    float rsq = rsqrtf(var + 1e-5f);
    f32x4 o;
    #pragma unroll
    for (int c = 0; c < 4; ++c) o[c] = (v[c] - mu) * rsq;
    ((f32x4*)(out + (size_t)row * DM))[t] = o;
}

extern "C" void kernel_launch(void* const* d_in, const int* in_sizes, int n_in,
                              void* d_out, int out_size, void* d_ws, size_t ws_size,
                              hipStream_t stream)
{
    const float* hidden = (const float*)d_in[0];
    const float* pos    = (const float*)d_in[1];
    const float* u      = (const float*)d_in[2];
    const float* vv     = (const float*)d_in[3];
    const float* memory = (const float*)d_in[5];
    const float* Wqkv   = (const float*)d_in[6];
    const float* Wpe    = (const float*)d_in[7];
    const float* Wout   = (const float*)d_in[8];
    float* out = (float*)d_out;

    char* w = (char*)d_ws;
    auto alloc = [&](size_t bytes) {
        void* p = (void*)w;
        w += (bytes + 255) & ~(size_t)255;
        return p;
    };
    // OPb (16.8 MB bf16) + ML (1 MB) alias the front pool (MH, PEA, WQKVT: 22 MB),
    // all dead before attn_fused runs.
    u16* MH    = (u16*)alloc((size_t)KLEN * DM * 2);
    u16* PEA   = (u16*)alloc((size_t)KLEN * DM * 2);
    u16* WQKVT = (u16*)alloc((size_t)3 * DM * DM * 2);
    u16* WPET  = (u16*)alloc((size_t)DM * DM * 2);
    u16* VB    = (u16*)alloc((size_t)KLEN * DM * 2);
    u16* QHAT  = (u16*)alloc((size_t)NHEAD * QLEN * 128 * 2);
    u16* KHAT  = (u16*)alloc((size_t)NHEAD * KLEN * 128 * 2);
    u16* VTb   = (u16*)alloc((size_t)NHEAD * DHEAD * KLEN * 2);
    u16* AVB   = (u16*)alloc((size_t)QLEN * DM * 2);
    float* RES = (float*)alloc((size_t)2 * QLEN * DM * 4);
    u16* WOUTT = (u16*)alloc((size_t)DM * DM * 2);
    u16* OPb   = (u16*)d_ws;
    float* ML  = (float*)((char*)d_ws + (size_t)4 * QLEN * NHEAD * 64 * 2);

    prep<<<8192 + 1280, 256, 0, stream>>>(memory, hidden, pos, Wqkv, Wpe, Wout,
                                          MH, PEA, WQKVT, WPET, WOUTT);
    gemm_qkvpe<<<896, 256, 0, stream>>>(MH, PEA, WQKVT, WPET, u, vv, QHAT, KHAT, VB);
    pack_vt<<<dim3(KLEN / 64, NHEAD), 256, 0, stream>>>(VB, VTb);
    attn_fused<<<dim3(1024), 256, 0, stream>>>(QHAT, KHAT, VTb, OPb, ML);
    attn_combine<<<dim3(QLEN * NHEAD * 8 / 256), 256, 0, stream>>>(OPb, ML, AVB);
    gemm_out<<<256, 256, 0, stream>>>(AVB, WOUTT, RES);
    ln_kernel<<<QLEN, 256, 0, stream>>>(hidden, RES, out);
}

// Round 17
// 159.013 us; speedup vs baseline: 1.0204x; 1.0100x over previous
//
#include <hip/hip_runtime.h>

typedef __attribute__((ext_vector_type(4))) float f32x4;
typedef __attribute__((ext_vector_type(16))) float f32x16;
typedef __attribute__((ext_vector_type(8))) short bf16x8;
typedef __attribute__((ext_vector_type(4))) unsigned short u16x4;
typedef unsigned short u16;

#define DM 1024
#define NHEAD 16
#define DHEAD 64
#define QLEN 2048
#define MLEN 2048
#define KLEN 4096
#define QSCALE 0.18033688011112042f   // 0.125 * log2(e): softmax in exp2 domain

__device__ __forceinline__ float bf2f(u16 u) {
    unsigned i = ((unsigned)u) << 16; float f; __builtin_memcpy(&f, &i, 4); return f;
}
__device__ __forceinline__ u16 f2bf(float f) {
    unsigned i; __builtin_memcpy(&i, &f, 4);
    unsigned r = i + 0x7fffu + ((i >> 16) & 1u);
    return (u16)(r >> 16);
}
__device__ __forceinline__ float exp2_fast(float x) {
#if __has_builtin(__builtin_amdgcn_exp2f)
    return __builtin_amdgcn_exp2f(x);
#else
    return exp2f(x);
#endif
}
__device__ __forceinline__ unsigned cvtpk_bf16(float lo, float hi) {
    unsigned r;
    asm("v_cvt_pk_bf16_f32 %0, %1, %2" : "=v"(r) : "v"(lo), "v"(hi));
    return r;
}
__device__ __forceinline__ void gl2lds16(const void* g, void* l) {
    __builtin_amdgcn_global_load_lds((const __attribute__((address_space(1))) void*)g,
                                     (__attribute__((address_space(3))) void*)l, 16, 0, 0);
}

// ---------------- prep: pack inputs to bf16 + transpose all 3 weights ----------------
__global__ __launch_bounds__(256) void prep(
    const float* __restrict__ memory, const float* __restrict__ hidden,
    const float* __restrict__ pos, const float* __restrict__ Wqkv,
    const float* __restrict__ Wpe, const float* __restrict__ Wout,
    u16* __restrict__ MH, u16* __restrict__ PEA,
    u16* __restrict__ WQKVT, u16* __restrict__ WPET, u16* __restrict__ WOUTT)
{
    __shared__ float ls[64][65];
    const int b = blockIdx.x, t = threadIdx.x;
    if (b < 8192) {
        size_t e = ((size_t)b * 256 + t) * 4;
        const size_t HALF = (size_t)KLEN * DM;
        f32x4 v; u16* dst;
        if (e < HALF) {
            size_t row = e >> 10, col = e & 1023;
            const float* src = (row < MLEN) ? (memory + row * DM) : (hidden + (row - MLEN) * DM);
            v = *(const f32x4*)(src + col);
            dst = MH + e;
        } else {
            size_t e2 = e - HALF;
            v = *(const f32x4*)(pos + e2);
            dst = PEA + e2;
        }
        u16x4 o;
        #pragma unroll
        for (int c = 0; c < 4; ++c) o[c] = f2bf(v[c]);
        *(u16x4*)dst = o;
        return;
    }
    int tb = b - 8192;
    const float* src; u16* dst; int N, bx, by;
    if (tb < 768)       { src = Wqkv; dst = WQKVT; N = 3 * DM; bx = tb % 48; by = tb / 48; }
    else if (tb < 1024) { int i = tb - 768;  src = Wpe;  dst = WPET;  N = DM; bx = i & 15; by = i >> 4; }
    else                { int i = tb - 1024; src = Wout; dst = WOUTT; N = DM; bx = i & 15; by = i >> 4; }
    const int n0 = bx * 64, k0 = by * 64;
    const int c = t & 63, rg = t >> 6;
    #pragma unroll
    for (int p = 0; p < 16; ++p) {
        int r = p * 4 + rg;
        ls[r][c] = src[(size_t)(k0 + r) * N + n0 + c];
    }
    __syncthreads();
    #pragma unroll
    for (int p = 0; p < 16; ++p) {
        int r = p * 4 + rg;
        dst[(size_t)(n0 + r) * DM + k0 + c] = f2bf(ls[c][r]);
    }
}

// ---------------- fused QKV + PE GEMM (1-phase, swizzled, 3 blocks/CU) ----------------
// V-region blocks additionally transpose their 128x128 tile through LDS and write VT
// directly (pack_vt kernel eliminated). XOR swizzle row^((col&7)<<4): bijective, same
// involution on write & read per col -> layout-proof; b128 reads stay 16B-aligned.
__global__ __launch_bounds__(256, 3) void gemm_qkvpe(
    const u16* __restrict__ MH, const u16* __restrict__ PEA,
    const u16* __restrict__ WQKVT, const u16* __restrict__ WPET,
    const float* __restrict__ u, const float* __restrict__ vv,
    u16* __restrict__ QHAT, u16* __restrict__ KHAT, u16* __restrict__ VT)
{
    __shared__ u16 lsbuf[2 * 128 * 64];   // 32 KB: [A|B] staging; reused for V transpose
    u16* lsA = lsbuf;
    u16* lsB = lsbuf + 8192;
    const int b = blockIdx.x;
    int row0, col0, region; const u16 *A, *B;
    if (b < 512)      { row0 = (b >> 4) * 128; col0 = 1024 + (b & 15) * 128; A = MH; B = WQKVT;
                        region = (col0 < 2048) ? 1 : 2; }
    else if (b < 640) { int i = b - 512; row0 = 2048 + (i >> 3) * 128; col0 = (i & 7) * 128;
                        A = MH; B = WQKVT; region = 0; }
    else              { int i = b - 640; row0 = (i >> 3) * 128; col0 = (i & 7) * 128;
                        A = PEA; B = WPET; region = 3; }
    const int tid = threadIdx.x, wave = tid >> 6, lane = tid & 63;
    const int blk = lane >> 4, ln = lane & 15;
    const int wr = (wave >> 1) << 6, wc = (wave & 1) << 6;
    const int rstage = lane >> 3;
    const int cswz = ((lane & 7) ^ rstage) * 8;   // source col, chunk ^= (row&7)

    f32x4 acc[4][4];
    #pragma unroll
    for (int i = 0; i < 4; ++i)
        #pragma unroll
        for (int j = 0; j < 4; ++j) acc[i][j] = f32x4{0.f, 0.f, 0.f, 0.f};

    for (int k0 = 0; k0 < DM; k0 += 64) {
        #pragma unroll
        for (int t = 0; t < 4; ++t) {
            int chunk = wave * 4 + t;
            int r = chunk * 8 + rstage;
            gl2lds16(A + (size_t)(row0 + r) * DM + k0 + cswz, lsA + chunk * 512);
            gl2lds16(B + (size_t)(col0 + r) * DM + k0 + cswz, lsB + chunk * 512);
        }
        __syncthreads();
        #pragma unroll
        for (int kk = 0; kk < 2; ++kk) {
            bf16x8 af[4], bfr[4];
            #pragma unroll
            for (int i = 0; i < 4; ++i) {
                int ro = wr + i * 16 + ln;
                af[i] = *(const bf16x8*)(lsA + ro * 64 + (((kk * 4 + blk) ^ (ro & 7)) * 8));
            }
            #pragma unroll
            for (int j = 0; j < 4; ++j) {
                int ro = wc + j * 16 + ln;
                bfr[j] = *(const bf16x8*)(lsB + ro * 64 + (((kk * 4 + blk) ^ (ro & 7)) * 8));
            }
            #pragma unroll
            for (int i = 0; i < 4; ++i)
                #pragma unroll
                for (int j = 0; j < 4; ++j)
                    acc[i][j] = __builtin_amdgcn_mfma_f32_16x16x32_bf16(af[i], bfr[j], acc[i][j], 0, 0, 0);
        }
        __syncthreads();
    }

    if (region == 2) {
        // ---- V: transpose 128x128 tile via LDS, write VT[h*64+d][k] directly ----
        // write T[col][row^x(col)], read T[col][k8^x(col)] -- same XOR per col.
        #pragma unroll
        for (int i = 0; i < 4; ++i)
            #pragma unroll
            for (int j = 0; j < 4; ++j) {
                int col = wc + j * 16 + ln;
                int x = (col & 7) << 4;
                #pragma unroll
                for (int r = 0; r < 4; ++r) {
                    int row = wr + i * 16 + blk * 4 + r;
                    lsbuf[col * 128 + (row ^ x)] = f2bf(acc[i][j][r]);
                }
            }
        __syncthreads();
        const int col = tid >> 1, hf = tid & 1;
        const int x = (col & 7) << 4;
        const int vcol = (col0 - 2048) + col;          // = h*64 + d
        u16* dst = VT + (size_t)vcol * KLEN + row0;
        #pragma unroll
        for (int j = 0; j < 8; ++j) {
            int k8 = hf * 64 + j * 8;
            bf16x8 v8 = *(const bf16x8*)(lsbuf + col * 128 + (k8 ^ x));
            *(bf16x8*)(dst + k8) = v8;
        }
        return;
    }

    #pragma unroll
    for (int i = 0; i < 4; ++i)
        #pragma unroll
        for (int j = 0; j < 4; ++j)
            #pragma unroll
            for (int r = 0; r < 4; ++r) {
                int row = row0 + wr + i * 16 + blk * 4 + r;
                int col = col0 + wc + j * 16 + ln;
                float val = acc[i][j][r];
                if (region == 0) {            // Q -> QHAT (both halves, u/v + exp2-scale)
                    int q = row - MLEN, h = col >> 6;
                    size_t base = ((size_t)h * QLEN + q) * 128 + (col & 63);
                    QHAT[base]      = f2bf((val + u[col]) * QSCALE);
                    QHAT[base + 64] = f2bf((val + vv[col]) * QSCALE);
                } else if (region == 1) {     // K -> KHAT[0:64]
                    int c = col - 1024, h = c >> 6;
                    KHAT[((size_t)h * KLEN + row) * 128 + (c & 63)] = f2bf(val);
                } else {                      // pe -> KHAT[64:128]
                    int h = col >> 6;
                    KHAT[((size_t)h * KLEN + row) * 128 + 64 + (col & 63)] = f2bf(val);
                }
            }
}

// ---------------- fused flash attention: key-split x4, V reg-staged + T5 setprio ----------------
__global__ __launch_bounds__(256, 4) void attn_fused(
    const u16* __restrict__ QHAT, const u16* __restrict__ KHAT,
    const u16* __restrict__ VT, u16* __restrict__ OPb, float* __restrict__ ML)
{
    // u16 units: K 2x4096 [0,8192), V 2x2560 [8192,13312), P 4x1280 [13312,18432)
    __shared__ __align__(16) u16 smem[18432];
    const int b = blockIdx.x;
    const int h  = ((b & 7) << 1) | ((b >> 3) & 1);
    const int ks = b >> 8;                            // key-quarter 0..3
    const int qb = (((b >> 4) & 15) + 4 * ks) & 15;   // scrambled for per-CU balance
    const int tid = threadIdx.x;
    const int wave = tid >> 6, lane = tid & 63;
    const int l31 = lane & 31, hi = lane >> 5;
    const int qrow0 = qb * 128 + wave * 32;
    u16* pb = smem + 13312 + wave * 1280;
    const int px = (l31 >> 3) & 3;

    const u16* khp = KHAT + (size_t)h * KLEN * 128;
    const u16* vhp = VT + (size_t)h * DHEAD * KLEN;

    const int nt = qb + 17;
    const int kbase = ks * nt * 32;
    const int vd = tid >> 2, vc = tid & 3;            // V staging geometry
    const int vslot = vc ^ ((vd >> 3) & 3);

    auto stage_load = [&](int buf, int kt) -> bf16x8 {
        const int k0 = kbase + kt * 32;
        u16* Kb = smem + buf * 4096;
        #pragma unroll
        for (int i = 0; i < 2; ++i) {
            int c = i * 256 + tid;
            int row = c >> 4, cgl = c & 15;
            int cs = cgl ^ (row & 15);
            gl2lds16(khp + ((size_t)(k0 + row) << 7) + cs * 8,
                     Kb + (size_t)(i * 256 + (tid & ~63)) * 8);
        }
        return *(const bf16x8*)(vhp + (size_t)vd * KLEN + k0 + vc * 8);
    };
    auto stage_write = [&](int buf, bf16x8 vr) {
        *(bf16x8*)(smem + 8192 + buf * 2560 + vd * 40 + vslot * 8) = vr;
    };

    bf16x8 qf[8];
    {
        const u16* qbase = QHAT + ((size_t)h * QLEN + qrow0 + l31) * 128 + hi * 8;
        #pragma unroll
        for (int kd = 0; kd < 8; ++kd) qf[kd] = *(const bf16x8*)(qbase + kd * 16);
    }

    f32x16 oacc[2];
    #pragma unroll
    for (int dg = 0; dg < 2; ++dg)
        #pragma unroll
        for (int r = 0; r < 16; ++r) oacc[dg][r] = 0.f;
    float mi = -1e30f, li = 0.f;

    const int qlim = qrow0 + 31 + MLEN;
    const int qsel = qrow0 + l31 + MLEN;

    bf16x8 vreg = stage_load(0, 0);
    asm volatile("s_waitcnt vmcnt(0)" ::: "memory");
    stage_write(0, vreg);
    __syncthreads();

    int cur = 0;
    for (int kt = 0; kt < nt; ++kt) {
        const int k0 = kbase + kt * 32;
        const bool pre = (kt + 1 < nt);
        if (pre) vreg = stage_load(cur ^ 1, kt + 1);

        if (k0 <= qlim) {
            // ---- QK^T (swapped): S^T[key][q], 8 chained MFMAs over d=128 ----
            f32x16 sacc;
            #pragma unroll
            for (int r = 0; r < 16; ++r) sacc[r] = 0.f;
            const u16* kb = smem + cur * 4096;
            const int rx = l31 & 15;
            __builtin_amdgcn_s_setprio(1);
            #pragma unroll
            for (int kd = 0; kd < 8; ++kd) {
                int cd = (kd * 2 + hi) ^ rx;
                bf16x8 kf = *(const bf16x8*)(kb + l31 * 128 + cd * 8);
                sacc = __builtin_amdgcn_mfma_f32_32x32x16_bf16(kf, qf[kd], sacc, 0, 0, 0);
            }
            __builtin_amdgcn_s_setprio(0);
            // ---- causal mask (rare tiles) ----
            if (k0 + 31 > qrow0 + MLEN) {
                const int keyb = k0 + 4 * hi;
                #pragma unroll
                for (int r = 0; r < 16; ++r) {
                    int key = keyb + (r & 3) + 8 * (r >> 2);
                    if (key > qsel) sacc[r] = -1e30f;
                }
            }
            // ---- in-register online softmax (exp2 domain, tree reductions) ----
            float mt;
            {
                f32x4 m4;
                #pragma unroll
                for (int r = 0; r < 4; ++r)
                    m4[r] = fmaxf(fmaxf(sacc[r], sacc[4 + r]), fmaxf(sacc[8 + r], sacc[12 + r]));
                mt = fmaxf(fmaxf(m4[0], m4[1]), fmaxf(m4[2], m4[3]));
            }
            mt = fmaxf(mt, __shfl_xor(mt, 32, 64));
            if (!__all(mt <= mi + 8.f)) {        // T13 defer-rescale, THR=8
                float mn = fmaxf(mi, mt);
                float corr = exp2_fast(mi - mn);
                mi = mn;
                li *= corr;
                #pragma unroll
                for (int dg = 0; dg < 2; ++dg)
                    #pragma unroll
                    for (int r = 0; r < 16; ++r) oacc[dg][r] *= corr;
            }
            #pragma unroll
            for (int r = 0; r < 16; ++r) sacc[r] = exp2_fast(sacc[r] - mi);
            float rs;
            {
                f32x4 s4;
                #pragma unroll
                for (int r = 0; r < 4; ++r)
                    s4[r] = (sacc[r] + sacc[4 + r]) + (sacc[8 + r] + sacc[12 + r]);
                rs = (s4[0] + s4[1]) + (s4[2] + s4[3]);
            }
            li += rs + __shfl_xor(rs, 32, 64);
            // ---- P -> LDS, 16B-chunk XOR swizzle ----
            {
                unsigned* pd = (unsigned*)(pb + (size_t)l31 * 40);
                #pragma unroll
                for (int b2 = 0; b2 < 4; ++b2)
                    #pragma unroll
                    for (int c = 0; c < 2; ++c)
                        pd[(b2 ^ px) * 4 + 2 * hi + c] =
                            cvtpk_bf16(sacc[4 * b2 + 2 * c], sacc[4 * b2 + 2 * c + 1]);
            }
            // ---- PV from padded V buffer ----
            __builtin_amdgcn_s_setprio(1);
            #pragma unroll
            for (int kkl = 0; kkl < 2; ++kkl) {
                bf16x8 pf = *(const bf16x8*)(pb + (size_t)l31 * 40 + ((kkl * 2 + hi) ^ px) * 8);
                #pragma unroll
                for (int dg = 0; dg < 2; ++dg) {
                    int vrow = dg * 32 + l31;
                    int cd = (kkl * 2 + hi) ^ ((l31 >> 3) & 3);
                    bf16x8 vf = *(const bf16x8*)(smem + 8192 + cur * 2560 + vrow * 40 + cd * 8);
                    oacc[dg] = __builtin_amdgcn_mfma_f32_32x32x16_bf16(vf, pf, oacc[dg], 0, 0, 0);
                }
            }
            __builtin_amdgcn_s_setprio(0);
        }
        asm volatile("s_waitcnt vmcnt(0)" ::: "memory");
        if (pre) stage_write(cur ^ 1, vreg);
        __syncthreads();
        cur ^= 1;
    }

    // ---- write partial (m, l, O-bf16) ----
    const int q = qrow0 + l31;
    unsigned* op32 = (unsigned*)(OPb + (((size_t)ks * QLEN + q) * NHEAD + h) * 64);
    #pragma unroll
    for (int dg = 0; dg < 2; ++dg) {
        union { f32x16 v; float f[16]; } oo;
        oo.v = oacc[dg];
        #pragma unroll
        for (int b2 = 0; b2 < 4; ++b2)
            #pragma unroll
            for (int c = 0; c < 2; ++c)
                op32[(dg * 32 + 8 * b2 + 4 * hi) / 2 + c] =
                    cvtpk_bf16(oo.f[4 * b2 + 2 * c], oo.f[4 * b2 + 2 * c + 1]);
    }
    if (!hi) {
        float* ml = ML + (((size_t)ks * QLEN + q) * NHEAD + h) * 2;
        ml[0] = mi; ml[1] = li;
    }
}

// ---------------- combine the 4 key-split partials -> AVB bf16 (exp2 domain) ----------------
__global__ __launch_bounds__(256) void attn_combine(
    const u16* __restrict__ OPb, const float* __restrict__ ML, u16* __restrict__ AVB)
{
    int idx = blockIdx.x * 256 + threadIdx.x;
    int d8 = (idx & 7) * 8;
    int h  = (idx >> 3) & 15;
    int q  = idx >> 7;
    float m[4], l[4], mf = -1e30f;
    #pragma unroll
    for (int ks = 0; ks < 4; ++ks) {
        const float* ml = ML + (((size_t)ks * QLEN + q) * NHEAD + h) * 2;
        m[ks] = ml[0]; l[ks] = ml[1];
        mf = fmaxf(mf, m[ks]);
    }
    float lsum = 0.f;
    float a[4];
    #pragma unroll
    for (int ks = 0; ks < 4; ++ks) {
        a[ks] = exp2_fast(m[ks] - mf);
        lsum += a[ks] * l[ks];
    }
    float inv = 1.f / lsum;
    float acc[8];
    #pragma unroll
    for (int j = 0; j < 8; ++j) acc[j] = 0.f;
    #pragma unroll
    for (int ks = 0; ks < 4; ++ks) {
        float w = a[ks] * inv;
        const u16* src = OPb + (((size_t)ks * QLEN + q) * NHEAD + h) * 64 + d8;
        u16x4 x0 = *(const u16x4*)(src);
        u16x4 x1 = *(const u16x4*)(src + 4);
        #pragma unroll
        for (int j = 0; j < 4; ++j) { acc[j] += w * bf2f(x0[j]); acc[4 + j] += w * bf2f(x1[j]); }
    }
    unsigned* A32 = (unsigned*)AVB;
    size_t base = ((size_t)q * DM + h * 64 + d8) >> 1;
    #pragma unroll
    for (int j = 0; j < 4; ++j)
        A32[base + j] = cvtpk_bf16(acc[2 * j], acc[2 * j + 1]);
}

// ---------------- out GEMM, split-K x2 (1-phase, swizzled) ----------------
__global__ __launch_bounds__(256, 3) void gemm_out(
    const u16* __restrict__ A, const u16* __restrict__ Bt, float* __restrict__ RES)
{
    __shared__ u16 lsA[128 * 64];
    __shared__ u16 lsB[128 * 64];
    const int b = blockIdx.x;
    const int tile = b >> 1, kh = b & 1;
    const int row0 = (tile >> 3) * 128, col0 = (tile & 7) * 128;
    const int tid = threadIdx.x, wave = tid >> 6, lane = tid & 63;
    const int blk = lane >> 4, ln = lane & 15;
    const int wr = (wave >> 1) << 6, wc = (wave & 1) << 6;
    const int rstage = lane >> 3;
    const int cswz = ((lane & 7) ^ rstage) * 8;

    f32x4 acc[4][4];
    #pragma unroll
    for (int i = 0; i < 4; ++i)
        #pragma unroll
        for (int j = 0; j < 4; ++j) acc[i][j] = f32x4{0.f, 0.f, 0.f, 0.f};

    for (int k0 = kh * 512; k0 < kh * 512 + 512; k0 += 64) {
        #pragma unroll
        for (int t = 0; t < 4; ++t) {
            int chunk = wave * 4 + t;
            int r = chunk * 8 + rstage;
            gl2lds16(A  + (size_t)(row0 + r) * DM + k0 + cswz, lsA + chunk * 512);
            gl2lds16(Bt + (size_t)(col0 + r) * DM + k0 + cswz, lsB + chunk * 512);
        }
        __syncthreads();
        #pragma unroll
        for (int kk = 0; kk < 2; ++kk) {
            bf16x8 af[4], bfr[4];
            #pragma unroll
            for (int i = 0; i < 4; ++i) {
                int ro = wr + i * 16 + ln;
                af[i] = *(const bf16x8*)(lsA + ro * 64 + (((kk * 4 + blk) ^ (ro & 7)) * 8));
            }
            #pragma unroll
            for (int j = 0; j < 4; ++j) {
                int ro = wc + j * 16 + ln;
                bfr[j] = *(const bf16x8*)(lsB + ro * 64 + (((kk * 4 + blk) ^ (ro & 7)) * 8));
            }
            #pragma unroll
            for (int i = 0; i < 4; ++i)
                #pragma unroll
                for (int j = 0; j < 4; ++j)
                    acc[i][j] = __builtin_amdgcn_mfma_f32_16x16x32_bf16(af[i], bfr[j], acc[i][j], 0, 0, 0);
        }
        __syncthreads();
    }
    float* C = RES + (size_t)kh * QLEN * DM;
    #pragma unroll
    for (int i = 0; i < 4; ++i)
        #pragma unroll
        for (int j = 0; j < 4; ++j)
            #pragma unroll
            for (int r = 0; r < 4; ++r) {
                int row = row0 + wr + i * 16 + blk * 4 + r;
                int col = col0 + wc + j * 16 + ln;
                C[(size_t)row * DM + col] = acc[i][j][r];
            }
}

// ---------------- layernorm over last dim: out = LN(hidden + RES0 + RES1) ----------------
__global__ __launch_bounds__(256) void ln_kernel(
    const float* __restrict__ hidden, const float* __restrict__ RES, float* __restrict__ out)
{
    const int row = blockIdx.x, t = threadIdx.x;
    const int wave = t >> 6, lane = t & 63;
    __shared__ float ws[8];
    f32x4 a = ((const f32x4*)(hidden + (size_t)row * DM))[t];
    f32x4 r0 = ((const f32x4*)(RES + (size_t)row * DM))[t];
    f32x4 r1 = ((const f32x4*)(RES + (size_t)(QLEN + row) * DM))[t];
    f32x4 v;
    #pragma unroll
    for (int c = 0; c < 4; ++c) v[c] = a[c] + r0[c] + r1[c];
    float s = v[0] + v[1] + v[2] + v[3];
    float s2 = v[0] * v[0] + v[1] * v[1] + v[2] * v[2] + v[3] * v[3];
    #pragma unroll
    for (int off = 1; off < 64; off <<= 1) {
        s += __shfl_xor(s, off, 64);
        s2 += __shfl_xor(s2, off, 64);
    }
    if (lane == 0) { ws[wave] = s; ws[4 + wave] = s2; }
    __syncthreads();
    float ts = ws[0] + ws[1] + ws[2] + ws[3];
    float ts2 = ws[4] + ws[5] + ws[6] + ws[7];
    float mu = ts * (1.f / DM);
    float var = ts2 * (1.f / DM) - mu * mu;
    float rsq = rsqrtf(var + 1e-5f);
    f32x4 o;
    #pragma unroll
    for (int c = 0; c < 4; ++c) o[c] = (v[c] - mu) * rsq;
    ((f32x4*)(out + (size_t)row * DM))[t] = o;
}

extern "C" void kernel_launch(void* const* d_in, const int* in_sizes, int n_in,
                              void* d_out, int out_size, void* d_ws, size_t ws_size,
                              hipStream_t stream)
{
    const float* hidden = (const float*)d_in[0];
    const float* pos    = (const float*)d_in[1];
    const float* u      = (const float*)d_in[2];
    const float* vv     = (const float*)d_in[3];
    const float* memory = (const float*)d_in[5];
    const float* Wqkv   = (const float*)d_in[6];
    const float* Wpe    = (const float*)d_in[7];
    const float* Wout   = (const float*)d_in[8];
    float* out = (float*)d_out;

    char* w = (char*)d_ws;
    auto alloc = [&](size_t bytes) {
        void* p = (void*)w;
        w += (bytes + 255) & ~(size_t)255;
        return p;
    };
    // OPb (16.8 MB bf16) + ML (1 MB) alias the front pool (MH, PEA, WQKVT: 22 MB),
    // all dead before attn_fused runs. VB slot retained for layout stability (unused).
    u16* MH    = (u16*)alloc((size_t)KLEN * DM * 2);
    u16* PEA   = (u16*)alloc((size_t)KLEN * DM * 2);
    u16* WQKVT = (u16*)alloc((size_t)3 * DM * DM * 2);
    u16* WPET  = (u16*)alloc((size_t)DM * DM * 2);
    u16* VB    = (u16*)alloc((size_t)KLEN * DM * 2);   // unused (V fused into gemm)
    u16* QHAT  = (u16*)alloc((size_t)NHEAD * QLEN * 128 * 2);
    u16* KHAT  = (u16*)alloc((size_t)NHEAD * KLEN * 128 * 2);
    u16* VTb   = (u16*)alloc((size_t)NHEAD * DHEAD * KLEN * 2);
    u16* AVB   = (u16*)alloc((size_t)QLEN * DM * 2);
    float* RES = (float*)alloc((size_t)2 * QLEN * DM * 4);
    u16* WOUTT = (u16*)alloc((size_t)DM * DM * 2);
    u16* OPb   = (u16*)d_ws;
    float* ML  = (float*)((char*)d_ws + (size_t)4 * QLEN * NHEAD * 64 * 2);
    (void)VB;

    prep<<<8192 + 1280, 256, 0, stream>>>(memory, hidden, pos, Wqkv, Wpe, Wout,
                                          MH, PEA, WQKVT, WPET, WOUTT);
    gemm_qkvpe<<<896, 256, 0, stream>>>(MH, PEA, WQKVT, WPET, u, vv, QHAT, KHAT, VTb);
    attn_fused<<<dim3(1024), 256, 0, stream>>>(QHAT, KHAT, VTb, OPb, ML);
    attn_combine<<<dim3(QLEN * NHEAD * 8 / 256), 256, 0, stream>>>(OPb, ML, AVB);
    gemm_out<<<256, 256, 0, stream>>>(AVB, WOUTT, RES);
    ln_kernel<<<QLEN, 256, 0, stream>>>(hidden, RES, out);
}

// Round 18
// 156.640 us; speedup vs baseline: 1.0359x; 1.0152x over previous
//
#include <hip/hip_runtime.h>

typedef __attribute__((ext_vector_type(4))) float f32x4;
typedef __attribute__((ext_vector_type(16))) float f32x16;
typedef __attribute__((ext_vector_type(8))) short bf16x8;
typedef __attribute__((ext_vector_type(4))) unsigned short u16x4;
typedef unsigned short u16;

#define DM 1024
#define NHEAD 16
#define DHEAD 64
#define QLEN 2048
#define MLEN 2048
#define KLEN 4096
#define QSCALE 0.18033688011112042f   // 0.125 * log2(e): softmax in exp2 domain

__device__ __forceinline__ float bf2f(u16 u) {
    unsigned i = ((unsigned)u) << 16; float f; __builtin_memcpy(&f, &i, 4); return f;
}
__device__ __forceinline__ u16 f2bf(float f) {
    unsigned i; __builtin_memcpy(&i, &f, 4);
    unsigned r = i + 0x7fffu + ((i >> 16) & 1u);
    return (u16)(r >> 16);
}
__device__ __forceinline__ float exp2_fast(float x) {
#if __has_builtin(__builtin_amdgcn_exp2f)
    return __builtin_amdgcn_exp2f(x);
#else
    return exp2f(x);
#endif
}
__device__ __forceinline__ unsigned cvtpk_bf16(float lo, float hi) {
    unsigned r;
    asm("v_cvt_pk_bf16_f32 %0, %1, %2" : "=v"(r) : "v"(lo), "v"(hi));
    return r;
}
__device__ __forceinline__ void gl2lds16(const void* g, void* l) {
    __builtin_amdgcn_global_load_lds((const __attribute__((address_space(1))) void*)g,
                                     (__attribute__((address_space(3))) void*)l, 16, 0, 0);
}

// ---------------- prep: pack inputs to bf16 + transpose all 3 weights ----------------
__global__ __launch_bounds__(256) void prep(
    const float* __restrict__ memory, const float* __restrict__ hidden,
    const float* __restrict__ pos, const float* __restrict__ Wqkv,
    const float* __restrict__ Wpe, const float* __restrict__ Wout,
    u16* __restrict__ MH, u16* __restrict__ PEA,
    u16* __restrict__ WQKVT, u16* __restrict__ WPET, u16* __restrict__ WOUTT)
{
    __shared__ float ls[64][65];
    const int b = blockIdx.x, t = threadIdx.x;
    if (b < 8192) {
        size_t e = ((size_t)b * 256 + t) * 4;
        const size_t HALF = (size_t)KLEN * DM;
        f32x4 v; u16* dst;
        if (e < HALF) {
            size_t row = e >> 10, col = e & 1023;
            const float* src = (row < MLEN) ? (memory + row * DM) : (hidden + (row - MLEN) * DM);
            v = *(const f32x4*)(src + col);
            dst = MH + e;
        } else {
            size_t e2 = e - HALF;
            v = *(const f32x4*)(pos + e2);
            dst = PEA + e2;
        }
        u16x4 o;
        #pragma unroll
        for (int c = 0; c < 4; ++c) o[c] = f2bf(v[c]);
        *(u16x4*)dst = o;
        return;
    }
    int tb = b - 8192;
    const float* src; u16* dst; int N, bx, by;
    if (tb < 768)       { src = Wqkv; dst = WQKVT; N = 3 * DM; bx = tb % 48; by = tb / 48; }
    else if (tb < 1024) { int i = tb - 768;  src = Wpe;  dst = WPET;  N = DM; bx = i & 15; by = i >> 4; }
    else                { int i = tb - 1024; src = Wout; dst = WOUTT; N = DM; bx = i & 15; by = i >> 4; }
    const int n0 = bx * 64, k0 = by * 64;
    const int c = t & 63, rg = t >> 6;
    #pragma unroll
    for (int p = 0; p < 16; ++p) {
        int r = p * 4 + rg;
        ls[r][c] = src[(size_t)(k0 + r) * N + n0 + c];
    }
    __syncthreads();
    #pragma unroll
    for (int p = 0; p < 16; ++p) {
        int r = p * 4 + rg;
        dst[(size_t)(n0 + r) * DM + k0 + c] = f2bf(ls[c][r]);
    }
}

// ---------------- fused QKV + PE GEMM (1-phase, swizzled, 3 blocks/CU) ----------------
// Block->tile maps are XCD-grouped (b&7 = XCD under round-robin dispatch): each XCD
// re-reads far fewer A panels -> L2-hit loads in the latency-exposed staging step.
// V-region blocks transpose their tile through LDS and write VT directly.
__global__ __launch_bounds__(256, 3) void gemm_qkvpe(
    const u16* __restrict__ MH, const u16* __restrict__ PEA,
    const u16* __restrict__ WQKVT, const u16* __restrict__ WPET,
    const float* __restrict__ u, const float* __restrict__ vv,
    u16* __restrict__ QHAT, u16* __restrict__ KHAT, u16* __restrict__ VT)
{
    __shared__ u16 lsbuf[2 * 128 * 64];   // 32 KB: [A|B] staging; reused for V transpose
    u16* lsA = lsbuf;
    u16* lsB = lsbuf + 8192;
    const int b = blockIdx.x;
    int row0, col0, region; const u16 *A, *B;
    if (b < 512) {        // KV: XCD x owns row-panels [(x>>1)*8,+8) x col-half (x&1)
        int x = b & 7, idx = b >> 3;          // idx 0..63
        int rp = (x >> 1) * 8 + (idx >> 3);   // 0..31
        int c  = (x & 1) * 8 + (idx & 7);     // 0..15
        row0 = rp * 128; col0 = 1024 + c * 128;
        A = MH; B = WQKVT; region = (c < 8) ? 1 : 2;
    }
    else if (b < 640) {   // Q: XCD x owns row-panels {2x, 2x+1}, all 8 cols
        int i = b - 512; int x = i & 7, idx = i >> 3;   // idx 0..15
        int rp = x * 2 + (idx >> 3);          // 0..15
        row0 = 2048 + rp * 128; col0 = (idx & 7) * 128;
        A = MH; B = WQKVT; region = 0;
    }
    else {                // PE: XCD x owns row-panels [4x,4x+4), all 8 cols
        int i = b - 640; int x = i & 7, idx = i >> 3;   // idx 0..31
        int rp = x * 4 + (idx >> 3);          // 0..31
        row0 = rp * 128; col0 = (idx & 7) * 128;
        A = PEA; B = WPET; region = 3;
    }
    const int tid = threadIdx.x, wave = tid >> 6, lane = tid & 63;
    const int blk = lane >> 4, ln = lane & 15;
    const int wr = (wave >> 1) << 6, wc = (wave & 1) << 6;
    const int rstage = lane >> 3;
    const int cswz = ((lane & 7) ^ rstage) * 8;   // source col, chunk ^= (row&7)

    f32x4 acc[4][4];
    #pragma unroll
    for (int i = 0; i < 4; ++i)
        #pragma unroll
        for (int j = 0; j < 4; ++j) acc[i][j] = f32x4{0.f, 0.f, 0.f, 0.f};

    for (int k0 = 0; k0 < DM; k0 += 64) {
        #pragma unroll
        for (int t = 0; t < 4; ++t) {
            int chunk = wave * 4 + t;
            int r = chunk * 8 + rstage;
            gl2lds16(A + (size_t)(row0 + r) * DM + k0 + cswz, lsA + chunk * 512);
            gl2lds16(B + (size_t)(col0 + r) * DM + k0 + cswz, lsB + chunk * 512);
        }
        __syncthreads();
        #pragma unroll
        for (int kk = 0; kk < 2; ++kk) {
            bf16x8 af[4], bfr[4];
            #pragma unroll
            for (int i = 0; i < 4; ++i) {
                int ro = wr + i * 16 + ln;
                af[i] = *(const bf16x8*)(lsA + ro * 64 + (((kk * 4 + blk) ^ (ro & 7)) * 8));
            }
            #pragma unroll
            for (int j = 0; j < 4; ++j) {
                int ro = wc + j * 16 + ln;
                bfr[j] = *(const bf16x8*)(lsB + ro * 64 + (((kk * 4 + blk) ^ (ro & 7)) * 8));
            }
            #pragma unroll
            for (int i = 0; i < 4; ++i)
                #pragma unroll
                for (int j = 0; j < 4; ++j)
                    acc[i][j] = __builtin_amdgcn_mfma_f32_16x16x32_bf16(af[i], bfr[j], acc[i][j], 0, 0, 0);
        }
        __syncthreads();
    }

    if (region == 2) {
        // ---- V: transpose 128x128 tile via LDS, write VT[h*64+d][k] directly ----
        #pragma unroll
        for (int i = 0; i < 4; ++i)
            #pragma unroll
            for (int j = 0; j < 4; ++j) {
                int col = wc + j * 16 + ln;
                int x = (col & 7) << 4;
                #pragma unroll
                for (int r = 0; r < 4; ++r) {
                    int row = wr + i * 16 + blk * 4 + r;
                    lsbuf[col * 128 + (row ^ x)] = f2bf(acc[i][j][r]);
                }
            }
        __syncthreads();
        const int col = tid >> 1, hf = tid & 1;
        const int x = (col & 7) << 4;
        const int vcol = (col0 - 2048) + col;          // = h*64 + d
        u16* dst = VT + (size_t)vcol * KLEN + row0;
        #pragma unroll
        for (int j = 0; j < 8; ++j) {
            int k8 = hf * 64 + j * 8;
            bf16x8 v8 = *(const bf16x8*)(lsbuf + col * 128 + (k8 ^ x));
            *(bf16x8*)(dst + k8) = v8;
        }
        return;
    }

    #pragma unroll
    for (int i = 0; i < 4; ++i)
        #pragma unroll
        for (int j = 0; j < 4; ++j)
            #pragma unroll
            for (int r = 0; r < 4; ++r) {
                int row = row0 + wr + i * 16 + blk * 4 + r;
                int col = col0 + wc + j * 16 + ln;
                float val = acc[i][j][r];
                if (region == 0) {            // Q -> QHAT (both halves, u/v + exp2-scale)
                    int q = row - MLEN, h = col >> 6;
                    size_t base = ((size_t)h * QLEN + q) * 128 + (col & 63);
                    QHAT[base]      = f2bf((val + u[col]) * QSCALE);
                    QHAT[base + 64] = f2bf((val + vv[col]) * QSCALE);
                } else if (region == 1) {     // K -> KHAT[0:64]
                    int c = col - 1024, h = c >> 6;
                    KHAT[((size_t)h * KLEN + row) * 128 + (c & 63)] = f2bf(val);
                } else {                      // pe -> KHAT[64:128]
                    int h = col >> 6;
                    KHAT[((size_t)h * KLEN + row) * 128 + 64 + (col & 63)] = f2bf(val);
                }
            }
}

// ---------------- fused flash attention: key-split x4, V reg-staged + T5 setprio ----------------
__global__ __launch_bounds__(256, 4) void attn_fused(
    const u16* __restrict__ QHAT, const u16* __restrict__ KHAT,
    const u16* __restrict__ VT, u16* __restrict__ OPb, float* __restrict__ ML)
{
    // u16 units: K 2x4096 [0,8192), V 2x2560 [8192,13312), P 4x1280 [13312,18432)
    __shared__ __align__(16) u16 smem[18432];
    const int b = blockIdx.x;
    const int h  = ((b & 7) << 1) | ((b >> 3) & 1);
    const int ks = b >> 8;                            // key-quarter 0..3
    const int qb = (((b >> 4) & 15) + 4 * ks) & 15;   // scrambled for per-CU balance
    const int tid = threadIdx.x;
    const int wave = tid >> 6, lane = tid & 63;
    const int l31 = lane & 31, hi = lane >> 5;
    const int qrow0 = qb * 128 + wave * 32;
    u16* pb = smem + 13312 + wave * 1280;
    const int px = (l31 >> 3) & 3;

    const u16* khp = KHAT + (size_t)h * KLEN * 128;
    const u16* vhp = VT + (size_t)h * DHEAD * KLEN;

    const int nt = qb + 17;
    const int kbase = ks * nt * 32;
    const int vd = tid >> 2, vc = tid & 3;            // V staging geometry
    const int vslot = vc ^ ((vd >> 3) & 3);

    auto stage_load = [&](int buf, int kt) -> bf16x8 {
        const int k0 = kbase + kt * 32;
        u16* Kb = smem + buf * 4096;
        #pragma unroll
        for (int i = 0; i < 2; ++i) {
            int c = i * 256 + tid;
            int row = c >> 4, cgl = c & 15;
            int cs = cgl ^ (row & 15);
            gl2lds16(khp + ((size_t)(k0 + row) << 7) + cs * 8,
                     Kb + (size_t)(i * 256 + (tid & ~63)) * 8);
        }
        return *(const bf16x8*)(vhp + (size_t)vd * KLEN + k0 + vc * 8);
    };
    auto stage_write = [&](int buf, bf16x8 vr) {
        *(bf16x8*)(smem + 8192 + buf * 2560 + vd * 40 + vslot * 8) = vr;
    };

    bf16x8 qf[8];
    {
        const u16* qbase = QHAT + ((size_t)h * QLEN + qrow0 + l31) * 128 + hi * 8;
        #pragma unroll
        for (int kd = 0; kd < 8; ++kd) qf[kd] = *(const bf16x8*)(qbase + kd * 16);
    }

    f32x16 oacc[2];
    #pragma unroll
    for (int dg = 0; dg < 2; ++dg)
        #pragma unroll
        for (int r = 0; r < 16; ++r) oacc[dg][r] = 0.f;
    float mi = -1e30f, li = 0.f;

    const int qlim = qrow0 + 31 + MLEN;
    const int qsel = qrow0 + l31 + MLEN;

    bf16x8 vreg = stage_load(0, 0);
    asm volatile("s_waitcnt vmcnt(0)" ::: "memory");
    stage_write(0, vreg);
    __syncthreads();

    int cur = 0;
    for (int kt = 0; kt < nt; ++kt) {
        const int k0 = kbase + kt * 32;
        const bool pre = (kt + 1 < nt);
        if (pre) vreg = stage_load(cur ^ 1, kt + 1);

        if (k0 <= qlim) {
            // ---- QK^T (swapped): S^T[key][q], 8 chained MFMAs over d=128 ----
            f32x16 sacc;
            #pragma unroll
            for (int r = 0; r < 16; ++r) sacc[r] = 0.f;
            const u16* kb = smem + cur * 4096;
            const int rx = l31 & 15;
            __builtin_amdgcn_s_setprio(1);
            #pragma unroll
            for (int kd = 0; kd < 8; ++kd) {
                int cd = (kd * 2 + hi) ^ rx;
                bf16x8 kf = *(const bf16x8*)(kb + l31 * 128 + cd * 8);
                sacc = __builtin_amdgcn_mfma_f32_32x32x16_bf16(kf, qf[kd], sacc, 0, 0, 0);
            }
            __builtin_amdgcn_s_setprio(0);
            // ---- causal mask (rare tiles) ----
            if (k0 + 31 > qrow0 + MLEN) {
                const int keyb = k0 + 4 * hi;
                #pragma unroll
                for (int r = 0; r < 16; ++r) {
                    int key = keyb + (r & 3) + 8 * (r >> 2);
                    if (key > qsel) sacc[r] = -1e30f;
                }
            }
            // ---- in-register online softmax (exp2 domain, tree reductions) ----
            float mt;
            {
                f32x4 m4;
                #pragma unroll
                for (int r = 0; r < 4; ++r)
                    m4[r] = fmaxf(fmaxf(sacc[r], sacc[4 + r]), fmaxf(sacc[8 + r], sacc[12 + r]));
                mt = fmaxf(fmaxf(m4[0], m4[1]), fmaxf(m4[2], m4[3]));
            }
            mt = fmaxf(mt, __shfl_xor(mt, 32, 64));
            if (!__all(mt <= mi + 8.f)) {        // T13 defer-rescale, THR=8
                float mn = fmaxf(mi, mt);
                float corr = exp2_fast(mi - mn);
                mi = mn;
                li *= corr;
                #pragma unroll
                for (int dg = 0; dg < 2; ++dg)
                    #pragma unroll
                    for (int r = 0; r < 16; ++r) oacc[dg][r] *= corr;
            }
            #pragma unroll
            for (int r = 0; r < 16; ++r) sacc[r] = exp2_fast(sacc[r] - mi);
            float rs;
            {
                f32x4 s4;
                #pragma unroll
                for (int r = 0; r < 4; ++r)
                    s4[r] = (sacc[r] + sacc[4 + r]) + (sacc[8 + r] + sacc[12 + r]);
                rs = (s4[0] + s4[1]) + (s4[2] + s4[3]);
            }
            li += rs + __shfl_xor(rs, 32, 64);
            // ---- P -> LDS, 16B-chunk XOR swizzle ----
            {
                unsigned* pd = (unsigned*)(pb + (size_t)l31 * 40);
                #pragma unroll
                for (int b2 = 0; b2 < 4; ++b2)
                    #pragma unroll
                    for (int c = 0; c < 2; ++c)
                        pd[(b2 ^ px) * 4 + 2 * hi + c] =
                            cvtpk_bf16(sacc[4 * b2 + 2 * c], sacc[4 * b2 + 2 * c + 1]);
            }
            // ---- PV from padded V buffer ----
            __builtin_amdgcn_s_setprio(1);
            #pragma unroll
            for (int kkl = 0; kkl < 2; ++kkl) {
                bf16x8 pf = *(const bf16x8*)(pb + (size_t)l31 * 40 + ((kkl * 2 + hi) ^ px) * 8);
                #pragma unroll
                for (int dg = 0; dg < 2; ++dg) {
                    int vrow = dg * 32 + l31;
                    int cd = (kkl * 2 + hi) ^ ((l31 >> 3) & 3);
                    bf16x8 vf = *(const bf16x8*)(smem + 8192 + cur * 2560 + vrow * 40 + cd * 8);
                    oacc[dg] = __builtin_amdgcn_mfma_f32_32x32x16_bf16(vf, pf, oacc[dg], 0, 0, 0);
                }
            }
            __builtin_amdgcn_s_setprio(0);
        }
        asm volatile("s_waitcnt vmcnt(0)" ::: "memory");
        if (pre) stage_write(cur ^ 1, vreg);
        __syncthreads();
        cur ^= 1;
    }

    // ---- write partial (m, l, O-bf16) ----
    const int q = qrow0 + l31;
    unsigned* op32 = (unsigned*)(OPb + (((size_t)ks * QLEN + q) * NHEAD + h) * 64);
    #pragma unroll
    for (int dg = 0; dg < 2; ++dg) {
        union { f32x16 v; float f[16]; } oo;
        oo.v = oacc[dg];
        #pragma unroll
        for (int b2 = 0; b2 < 4; ++b2)
            #pragma unroll
            for (int c = 0; c < 2; ++c)
                op32[(dg * 32 + 8 * b2 + 4 * hi) / 2 + c] =
                    cvtpk_bf16(oo.f[4 * b2 + 2 * c], oo.f[4 * b2 + 2 * c + 1]);
    }
    if (!hi) {
        float* ml = ML + (((size_t)ks * QLEN + q) * NHEAD + h) * 2;
        ml[0] = mi; ml[1] = li;
    }
}

// ---------------- combine the 4 key-split partials -> AVB bf16 (exp2 domain) ----------------
__global__ __launch_bounds__(256) void attn_combine(
    const u16* __restrict__ OPb, const float* __restrict__ ML, u16* __restrict__ AVB)
{
    int idx = blockIdx.x * 256 + threadIdx.x;
    int d8 = (idx & 7) * 8;
    int h  = (idx >> 3) & 15;
    int q  = idx >> 7;
    float m[4], l[4], mf = -1e30f;
    #pragma unroll
    for (int ks = 0; ks < 4; ++ks) {
        const float* ml = ML + (((size_t)ks * QLEN + q) * NHEAD + h) * 2;
        m[ks] = ml[0]; l[ks] = ml[1];
        mf = fmaxf(mf, m[ks]);
    }
    float lsum = 0.f;
    float a[4];
    #pragma unroll
    for (int ks = 0; ks < 4; ++ks) {
        a[ks] = exp2_fast(m[ks] - mf);
        lsum += a[ks] * l[ks];
    }
    float inv = 1.f / lsum;
    float acc[8];
    #pragma unroll
    for (int j = 0; j < 8; ++j) acc[j] = 0.f;
    #pragma unroll
    for (int ks = 0; ks < 4; ++ks) {
        float w = a[ks] * inv;
        const u16* src = OPb + (((size_t)ks * QLEN + q) * NHEAD + h) * 64 + d8;
        u16x4 x0 = *(const u16x4*)(src);
        u16x4 x1 = *(const u16x4*)(src + 4);
        #pragma unroll
        for (int j = 0; j < 4; ++j) { acc[j] += w * bf2f(x0[j]); acc[4 + j] += w * bf2f(x1[j]); }
    }
    unsigned* A32 = (unsigned*)AVB;
    size_t base = ((size_t)q * DM + h * 64 + d8) >> 1;
    #pragma unroll
    for (int j = 0; j < 4; ++j)
        A32[base + j] = cvtpk_bf16(acc[2 * j], acc[2 * j + 1]);
}

// ---------------- out GEMM, split-K x2 (1-phase, swizzled) ----------------
__global__ __launch_bounds__(256, 3) void gemm_out(
    const u16* __restrict__ A, const u16* __restrict__ Bt, float* __restrict__ RES)
{
    __shared__ u16 lsA[128 * 64];
    __shared__ u16 lsB[128 * 64];
    const int b = blockIdx.x;
    const int tile = b >> 1, kh = b & 1;
    const int row0 = (tile >> 3) * 128, col0 = (tile & 7) * 128;
    const int tid = threadIdx.x, wave = tid >> 6, lane = tid & 63;
    const int blk = lane >> 4, ln = lane & 15;
    const int wr = (wave >> 1) << 6, wc = (wave & 1) << 6;
    const int rstage = lane >> 3;
    const int cswz = ((lane & 7) ^ rstage) * 8;

    f32x4 acc[4][4];
    #pragma unroll
    for (int i = 0; i < 4; ++i)
        #pragma unroll
        for (int j = 0; j < 4; ++j) acc[i][j] = f32x4{0.f, 0.f, 0.f, 0.f};

    for (int k0 = kh * 512; k0 < kh * 512 + 512; k0 += 64) {
        #pragma unroll
        for (int t = 0; t < 4; ++t) {
            int chunk = wave * 4 + t;
            int r = chunk * 8 + rstage;
            gl2lds16(A  + (size_t)(row0 + r) * DM + k0 + cswz, lsA + chunk * 512);
            gl2lds16(Bt + (size_t)(col0 + r) * DM + k0 + cswz, lsB + chunk * 512);
        }
        __syncthreads();
        #pragma unroll
        for (int kk = 0; kk < 2; ++kk) {
            bf16x8 af[4], bfr[4];
            #pragma unroll
            for (int i = 0; i < 4; ++i) {
                int ro = wr + i * 16 + ln;
                af[i] = *(const bf16x8*)(lsA + ro * 64 + (((kk * 4 + blk) ^ (ro & 7)) * 8));
            }
            #pragma unroll
            for (int j = 0; j < 4; ++j) {
                int ro = wc + j * 16 + ln;
                bfr[j] = *(const bf16x8*)(lsB + ro * 64 + (((kk * 4 + blk) ^ (ro & 7)) * 8));
            }
            #pragma unroll
            for (int i = 0; i < 4; ++i)
                #pragma unroll
                for (int j = 0; j < 4; ++j)
                    acc[i][j] = __builtin_amdgcn_mfma_f32_16x16x32_bf16(af[i], bfr[j], acc[i][j], 0, 0, 0);
        }
        __syncthreads();
    }
    float* C = RES + (size_t)kh * QLEN * DM;
    #pragma unroll
    for (int i = 0; i < 4; ++i)
        #pragma unroll
        for (int j = 0; j < 4; ++j)
            #pragma unroll
            for (int r = 0; r < 4; ++r) {
                int row = row0 + wr + i * 16 + blk * 4 + r;
                int col = col0 + wc + j * 16 + ln;
                C[(size_t)row * DM + col] = acc[i][j][r];
            }
}

// ---------------- layernorm over last dim: out = LN(hidden + RES0 + RES1) ----------------
__global__ __launch_bounds__(256) void ln_kernel(
    const float* __restrict__ hidden, const float* __restrict__ RES, float* __restrict__ out)
{
    const int row = blockIdx.x, t = threadIdx.x;
    const int wave = t >> 6, lane = t & 63;
    __shared__ float ws[8];
    f32x4 a = ((const f32x4*)(hidden + (size_t)row * DM))[t];
    f32x4 r0 = ((const f32x4*)(RES + (size_t)row * DM))[t];
    f32x4 r1 = ((const f32x4*)(RES + (size_t)(QLEN + row) * DM))[t];
    f32x4 v;
    #pragma unroll
    for (int c = 0; c < 4; ++c) v[c] = a[c] + r0[c] + r1[c];
    float s = v[0] + v[1] + v[2] + v[3];
    float s2 = v[0] * v[0] + v[1] * v[1] + v[2] * v[2] + v[3] * v[3];
    #pragma unroll
    for (int off = 1; off < 64; off <<= 1) {
        s += __shfl_xor(s, off, 64);
        s2 += __shfl_xor(s2, off, 64);
    }
    if (lane == 0) { ws[wave] = s; ws[4 + wave] = s2; }
    __syncthreads();
    float ts = ws[0] + ws[1] + ws[2] + ws[3];
    float ts2 = ws[4] + ws[5] + ws[6] + ws[7];
    float mu = ts * (1.f / DM);
    float var = ts2 * (1.f / DM) - mu * mu;
    float rsq = rsqrtf(var + 1e-5f);
    f32x4 o;
    #pragma unroll
    for (int c = 0; c < 4; ++c) o[c] = (v[c] - mu) * rsq;
    ((f32x4*)(out + (size_t)row * DM))[t] = o;
}

extern "C" void kernel_launch(void* const* d_in, const int* in_sizes, int n_in,
                              void* d_out, int out_size, void* d_ws, size_t ws_size,
                              hipStream_t stream)
{
    const float* hidden = (const float*)d_in[0];
    const float* pos    = (const float*)d_in[1];
    const float* u      = (const float*)d_in[2];
    const float* vv     = (const float*)d_in[3];
    const float* memory = (const float*)d_in[5];
    const float* Wqkv   = (const float*)d_in[6];
    const float* Wpe    = (const float*)d_in[7];
    const float* Wout   = (const float*)d_in[8];
    float* out = (float*)d_out;

    char* w = (char*)d_ws;
    auto alloc = [&](size_t bytes) {
        void* p = (void*)w;
        w += (bytes + 255) & ~(size_t)255;
        return p;
    };
    // OPb (16.8 MB bf16) + ML (1 MB) alias the front pool (MH, PEA, WQKVT: 22 MB),
    // all dead before attn_fused runs. VB slot retained for layout stability (unused).
    u16* MH    = (u16*)alloc((size_t)KLEN * DM * 2);
    u16* PEA   = (u16*)alloc((size_t)KLEN * DM * 2);
    u16* WQKVT = (u16*)alloc((size_t)3 * DM * DM * 2);
    u16* WPET  = (u16*)alloc((size_t)DM * DM * 2);
    u16* VB    = (u16*)alloc((size_t)KLEN * DM * 2);   // unused (V fused into gemm)
    u16* QHAT  = (u16*)alloc((size_t)NHEAD * QLEN * 128 * 2);
    u16* KHAT  = (u16*)alloc((size_t)NHEAD * KLEN * 128 * 2);
    u16* VTb   = (u16*)alloc((size_t)NHEAD * DHEAD * KLEN * 2);
    u16* AVB   = (u16*)alloc((size_t)QLEN * DM * 2);
    float* RES = (float*)alloc((size_t)2 * QLEN * DM * 4);
    u16* WOUTT = (u16*)alloc((size_t)DM * DM * 2);
    u16* OPb   = (u16*)d_ws;
    float* ML  = (float*)((char*)d_ws + (size_t)4 * QLEN * NHEAD * 64 * 2);
    (void)VB;

    prep<<<8192 + 1280, 256, 0, stream>>>(memory, hidden, pos, Wqkv, Wpe, Wout,
                                          MH, PEA, WQKVT, WPET, WOUTT);
    gemm_qkvpe<<<896, 256, 0, stream>>>(MH, PEA, WQKVT, WPET, u, vv, QHAT, KHAT, VTb);
    attn_fused<<<dim3(1024), 256, 0, stream>>>(QHAT, KHAT, VTb, OPb, ML);
    attn_combine<<<dim3(QLEN * NHEAD * 8 / 256), 256, 0, stream>>>(OPb, ML, AVB);
    gemm_out<<<256, 256, 0, stream>>>(AVB, WOUTT, RES);
    ln_kernel<<<QLEN, 256, 0, stream>>>(hidden, RES, out);
}